// Round 6
// baseline (326.457 us; speedup 1.0000x reference)
//
#include <hip/hip_runtime.h>
#include <hip/hip_fp16.h>

#define HID 128
#define EMB 64
#define NG  8192
#define NCLS 16
#define SCAN_T 4096
#define MMB 64        // nodes per matmul block

// ---------------- degree ----------------
__global__ void k_deg(const int* __restrict__ dst, int E, int* __restrict__ deg) {
    int i = blockIdx.x * 256 + threadIdx.x;
    if (i < E) atomicAdd(&deg[dst[i]], 1);
}

__global__ void k_dinv(const int* __restrict__ deg, float* __restrict__ dinv, int N) {
    int i = blockIdx.x * 256 + threadIdx.x;
    if (i < N) dinv[i] = rsqrtf((float)(deg[i] + 1));  // +1 self-loop
}

// ---------------- exclusive scan of deg -> rowptr ----------------
__global__ void k_scanA(const int* __restrict__ deg, int* __restrict__ tsum, int N, int seg) {
    int t = blockIdx.x * 256 + threadIdx.x;
    int beg = t * seg, end = min(beg + seg, N);
    int s = 0;
    for (int i = beg; i < end; ++i) s += deg[i];
    tsum[t] = s;
}

__global__ void k_scanB(int* __restrict__ tsum) {
    __shared__ int sh[256];
    int tid = threadIdx.x;
    const int PER = SCAN_T / 256;
    int vals[PER];
    int local = 0;
    int base = tid * PER;
#pragma unroll
    for (int i = 0; i < PER; ++i) { vals[i] = tsum[base + i]; local += vals[i]; }
    sh[tid] = local; __syncthreads();
    for (int d = 1; d < 256; d <<= 1) {
        int v = (tid >= d) ? sh[tid - d] : 0;
        __syncthreads();
        sh[tid] += v;
        __syncthreads();
    }
    int off = sh[tid] - local;
#pragma unroll
    for (int i = 0; i < PER; ++i) { int v = vals[i]; tsum[base + i] = off; off += v; }
}

__global__ void k_scanC(const int* __restrict__ deg, const int* __restrict__ tsum,
                        int* __restrict__ rowptr, int N, int seg, int E) {
    int t = blockIdx.x * 256 + threadIdx.x;
    int beg = t * seg, end = min(beg + seg, N);
    int off = tsum[t];
    for (int i = beg; i < end; ++i) { rowptr[i] = off; off += deg[i]; }
    if (t == 0) rowptr[N] = E;
}

// ---------------- CSR fill: packed {src, vid, w_bits, 0} per edge ----------------
__global__ void k_fill(const int* __restrict__ src, const int* __restrict__ dst,
                       const int* __restrict__ ids, const float* __restrict__ dinv,
                       const int* __restrict__ rowptr, int* __restrict__ cursor,
                       int4* __restrict__ csr_pack, int E) {
    int e = blockIdx.x * 256 + threadIdx.x;
    if (e < E) {
        int s = src[e], d = dst[e];
        int pos = atomicAdd(&cursor[d], 1);
        int p = rowptr[d] + pos;
        csr_pack[p] = make_int4(s, ids[s], __float_as_int(dinv[s]), 0);
    }
}

// ---------------- graph segment boundaries from sorted batch ----------------
__global__ void k_bounds(const int* __restrict__ batch, int* __restrict__ gstart, int N) {
    int n = blockIdx.x * 256 + threadIdx.x;
    if (n > N) return;
    int bc = (n < N) ? batch[n] : NG;
    int bp = (n > 0) ? batch[n - 1] : -1;
    for (int g = bp + 1; g <= bc; ++g) gstart[g] = n;
}

// ---------------- layer-1 propagate in 64-dim embed space (L2-resident table) ----
// agg0[d] = dd * ( dd*embed[ids[d]] + sum_e w_e * embed[vid_e] )
__global__ void k_gather64(const int* __restrict__ ids, const float* __restrict__ embed,
                           const int4* __restrict__ csr_pack,
                           const int* __restrict__ rowptr, const float* __restrict__ dinv,
                           float* __restrict__ agg0, int N) {
    int wid = (blockIdx.x * blockDim.x + threadIdx.x) >> 6;  // one wave per node
    if (wid >= N) return;
    int lane = threadIdx.x & 63;
    int d = wid;
    int beg = rowptr[d], end = rowptr[d + 1];
    float dd = dinv[d];
    float acc = embed[(size_t)ids[d] * EMB + lane] * dd;
    int i = beg;
    for (; i + 4 <= end; i += 4) {
        int4 p0 = csr_pack[i], p1 = csr_pack[i + 1], p2 = csr_pack[i + 2], p3 = csr_pack[i + 3];
        float e0 = embed[(size_t)p0.y * EMB + lane];
        float e1 = embed[(size_t)p1.y * EMB + lane];
        float e2 = embed[(size_t)p2.y * EMB + lane];
        float e3 = embed[(size_t)p3.y * EMB + lane];
        acc = fmaf(e0, __int_as_float(p0.z), acc);
        acc = fmaf(e1, __int_as_float(p1.z), acc);
        acc = fmaf(e2, __int_as_float(p2.z), acc);
        acc = fmaf(e3, __int_as_float(p3.z), acc);
    }
    for (; i < end; ++i) {
        int4 p = csr_pack[i];
        acc = fmaf(embed[(size_t)p.y * EMB + lane], __int_as_float(p.z), acc);
    }
    agg0[(size_t)d * EMB + lane] = acc * dd;
}

// ---------------- layer-1 matmul: relu([Nx64]@[64x128] + b1) ----------------
__global__ __launch_bounds__(256) void k_mm1(const float* __restrict__ in,
                                             const float* __restrict__ W1,
                                             const float* __restrict__ b1,
                                             float* __restrict__ out, int N) {
    __shared__ float rows_t[EMB][64];    // transposed [k][n], 16 KB, no pad needed
    __shared__ float Ws[EMB * HID];      // full W1, 32 KB
    int tid = threadIdx.x;
    int base = blockIdx.x * MMB;
    {
        const float4* wp = (const float4*)W1;
        float4* wsp = (float4*)Ws;
#pragma unroll
        for (int j = 0; j < 8; ++j) wsp[tid + 256 * j] = wp[tid + 256 * j];
    }
    // stage rows transposed: thread -> node tid&63, k-range (tid>>6)*16
    {
        int n = tid & 63;
        int k0 = (tid >> 6) * 16;
        int node = base + n; if (node >= N) node = N - 1;
        const float4* ep = (const float4*)&in[(size_t)node * EMB + k0];
#pragma unroll
        for (int j = 0; j < 4; ++j) {
            float4 v = ep[j];
            int k = k0 + j * 4;
            rows_t[k + 0][n] = v.x; rows_t[k + 1][n] = v.y;
            rows_t[k + 2][n] = v.z; rows_t[k + 3][n] = v.w;
        }
    }
    __syncthreads();
    int n8 = (tid & 7) * 8;
    int c4 = (tid >> 3) * 4;
    float acc[8][4];
#pragma unroll
    for (int i = 0; i < 8; ++i)
#pragma unroll
        for (int j = 0; j < 4; ++j) acc[i][j] = 0.f;
    for (int k = 0; k < EMB; ++k) {
        float4 w = *(const float4*)&Ws[k * HID + c4];
        float4 r0 = *(const float4*)&rows_t[k][n8];
        float4 r1 = *(const float4*)&rows_t[k][n8 + 4];
        float rr[8] = {r0.x, r0.y, r0.z, r0.w, r1.x, r1.y, r1.z, r1.w};
#pragma unroll
        for (int i = 0; i < 8; ++i) {
            acc[i][0] = fmaf(rr[i], w.x, acc[i][0]);
            acc[i][1] = fmaf(rr[i], w.y, acc[i][1]);
            acc[i][2] = fmaf(rr[i], w.z, acc[i][2]);
            acc[i][3] = fmaf(rr[i], w.w, acc[i][3]);
        }
    }
    float4 bb = *(const float4*)&b1[c4];
#pragma unroll
    for (int i = 0; i < 8; ++i) {
        int node = base + n8 + i;
        if (node < N)
            *(float4*)&out[(size_t)node * HID + c4] =
                make_float4(fmaxf(acc[i][0] + bb.x, 0.f), fmaxf(acc[i][1] + bb.y, 0.f),
                            fmaxf(acc[i][2] + bb.z, 0.f), fmaxf(acc[i][3] + bb.w, 0.f));
    }
}

// ---------------- layer-2 matmul: [Nx128]@[128x128] -> fp16, prescaled by dinv ----
__global__ __launch_bounds__(256) void k_mm2(const float* __restrict__ in,
                                             const float* __restrict__ W,
                                             const float* __restrict__ dinv,
                                             __half* __restrict__ out, int N) {
    __shared__ float rows_t[HID][64];    // 32 KB, no pad needed
    __shared__ float Ws[32 * HID];       // 16 KB
    int tid = threadIdx.x;
    int base = blockIdx.x * MMB;
    // stage rows transposed: thread -> node tid&63, k-range (tid>>6)*32
    {
        int n = tid & 63;
        int k0 = (tid >> 6) * 32;
        int node = base + n; if (node >= N) node = N - 1;
        const float4* ip = (const float4*)&in[(size_t)node * HID + k0];
#pragma unroll
        for (int j = 0; j < 8; ++j) {
            float4 v = ip[j];
            int k = k0 + j * 4;
            rows_t[k + 0][n] = v.x; rows_t[k + 1][n] = v.y;
            rows_t[k + 2][n] = v.z; rows_t[k + 3][n] = v.w;
        }
    }
    int n8 = (tid & 7) * 8;
    int c4 = (tid >> 3) * 4;
    float acc[8][4];
#pragma unroll
    for (int i = 0; i < 8; ++i)
#pragma unroll
        for (int j = 0; j < 4; ++j) acc[i][j] = 0.f;
    for (int q = 0; q < 4; ++q) {
        __syncthreads();
        {
            const float4* wp = (const float4*)&W[q * 32 * HID];
            float4* wsp = (float4*)Ws;
#pragma unroll
            for (int j = 0; j < 4; ++j) wsp[tid + 256 * j] = wp[tid + 256 * j];
        }
        __syncthreads();
        for (int k = 0; k < 32; ++k) {
            float4 w = *(const float4*)&Ws[k * HID + c4];
            float4 r0 = *(const float4*)&rows_t[q * 32 + k][n8];
            float4 r1 = *(const float4*)&rows_t[q * 32 + k][n8 + 4];
            float rr[8] = {r0.x, r0.y, r0.z, r0.w, r1.x, r1.y, r1.z, r1.w};
#pragma unroll
            for (int i = 0; i < 8; ++i) {
                acc[i][0] = fmaf(rr[i], w.x, acc[i][0]);
                acc[i][1] = fmaf(rr[i], w.y, acc[i][1]);
                acc[i][2] = fmaf(rr[i], w.z, acc[i][2]);
                acc[i][3] = fmaf(rr[i], w.w, acc[i][3]);
            }
        }
    }
#pragma unroll
    for (int i = 0; i < 8; ++i) {
        int node = base + n8 + i;
        if (node < N) {
            float sc = dinv[node];
            union { __half2 h[2]; uint2 u; } pk;
            pk.h[0] = __floats2half2_rn(acc[i][0] * sc, acc[i][1] * sc);
            pk.h[1] = __floats2half2_rn(acc[i][2] * sc, acc[i][3] * sc);
            *(uint2*)&out[(size_t)node * HID + c4] = pk.u;
        }
    }
}

// ---------------- layer-2 gather: out[d] = relu(dd*(h2[d]+sum h2[s]) + b) ----
__global__ void k_gather128h(const __half* __restrict__ h2, const int4* __restrict__ csr_pack,
                             const int* __restrict__ rowptr, const float* __restrict__ dinv,
                             const float* __restrict__ bias, float* __restrict__ out, int N) {
    int wid = (blockIdx.x * blockDim.x + threadIdx.x) >> 6;  // one wave per node
    if (wid >= N) return;
    int lane = threadIdx.x & 63;
    int d = wid;
    int beg = rowptr[d], end = rowptr[d + 1];
    float dd = dinv[d];
    const __half2* hr = (const __half2*)h2;   // row = 64 half2
    float2 f = __half22float2(hr[(size_t)d * 64 + lane]);
    float ax = f.x, ay = f.y;
    int i = beg;
    for (; i + 4 <= end; i += 4) {
        int s0 = csr_pack[i].x, s1 = csr_pack[i + 1].x;
        int s2 = csr_pack[i + 2].x, s3 = csr_pack[i + 3].x;
        float2 v0 = __half22float2(hr[(size_t)s0 * 64 + lane]);
        float2 v1 = __half22float2(hr[(size_t)s1 * 64 + lane]);
        float2 v2 = __half22float2(hr[(size_t)s2 * 64 + lane]);
        float2 v3 = __half22float2(hr[(size_t)s3 * 64 + lane]);
        ax += (v0.x + v1.x) + (v2.x + v3.x);
        ay += (v0.y + v1.y) + (v2.y + v3.y);
    }
    for (; i < end; ++i) {
        float2 v = __half22float2(hr[(size_t)csr_pack[i].x * 64 + lane]);
        ax += v.x; ay += v.y;
    }
    float2 b = ((const float2*)bias)[lane];
    float2 r;
    r.x = fmaxf(fmaf(ax, dd, b.x), 0.f);
    r.y = fmaxf(fmaf(ay, dd, b.y), 0.f);
    ((float2*)out)[(size_t)d * 64 + lane] = r;
}

// ---------------- fused mean-pool + head: one wave per graph ----------------
__global__ void k_pool2(const float* __restrict__ x, const int* __restrict__ gstart,
                        const float* __restrict__ Wout, const float* __restrict__ bout,
                        float* __restrict__ out) {
    int wid = (blockIdx.x * blockDim.x + threadIdx.x) >> 6;  // graph id
    if (wid >= NG) return;
    int lane = threadIdx.x & 63;
    int beg = gstart[wid], end = gstart[wid + 1];
    const float2* rows = (const float2*)x;
    float sx = 0.f, sy = 0.f;
    for (int n = beg; n < end; ++n) {
        float2 v = rows[(size_t)n * 64 + lane];
        sx += v.x; sy += v.y;
    }
    float inv = (end > beg) ? 1.f / (float)(end - beg) : 1.f;
    sx *= inv; sy *= inv;
    float wo0[NCLS], wo1[NCLS];
    {
        const float4* p0 = (const float4*)&Wout[(size_t)(2 * lane) * NCLS];
        const float4* p1 = (const float4*)&Wout[(size_t)(2 * lane + 1) * NCLS];
#pragma unroll
        for (int j = 0; j < 4; ++j) {
            float4 a = p0[j]; wo0[4*j] = a.x; wo0[4*j+1] = a.y; wo0[4*j+2] = a.z; wo0[4*j+3] = a.w;
            float4 b = p1[j]; wo1[4*j] = b.x; wo1[4*j+1] = b.y; wo1[4*j+2] = b.z; wo1[4*j+3] = b.w;
        }
    }
#pragma unroll
    for (int c = 0; c < NCLS; ++c) {
        float p = fmaf(sx, wo0[c], sy * wo1[c]);
#pragma unroll
        for (int s = 1; s < 64; s <<= 1) p += __shfl_xor(p, s, 64);
        if (lane == c) out[(size_t)wid * NCLS + c] = p + bout[c];
    }
}

static inline size_t align_up(size_t v, size_t a) { return (v + a - 1) & ~(a - 1); }

extern "C" void kernel_launch(void* const* d_in, const int* in_sizes, int n_in,
                              void* d_out, int out_size, void* d_ws, size_t ws_size,
                              hipStream_t stream) {
    const int*   node_ids = (const int*)d_in[0];
    const int*   edge     = (const int*)d_in[1];
    const int*   batch    = (const int*)d_in[2];
    const float* embed    = (const float*)d_in[3];
    const float* W1       = (const float*)d_in[4];
    const float* b1       = (const float*)d_in[5];
    const float* W2       = (const float*)d_in[6];
    const float* b2       = (const float*)d_in[7];
    const float* Wout     = (const float*)d_in[8];
    const float* bout     = (const float*)d_in[9];
    float* out = (float*)d_out;

    const int N = in_sizes[0];
    const int E = in_sizes[1] / 2;
    const int seg = (N + SCAN_T - 1) / SCAN_T;

    // 256B-aligned workspace layout; h2 overlays agg0 (dead after k_mm1)
    char* wsb = (char*)d_ws;
    size_t off = 0;
    float* dinv     = (float*)(wsb + off); off = align_up(off + (size_t)N * 4, 256);
    int*   deg      = (int*)(wsb + off);   off = align_up(off + (size_t)N * 4, 256);
    int*   rowptr   = (int*)(wsb + off);   off = align_up(off + (size_t)(N + 1) * 4, 256);
    int*   tsum     = (int*)(wsb + off);   off = align_up(off + (size_t)SCAN_T * 4, 256);
    int*   gstart   = (int*)(wsb + off);   off = align_up(off + (size_t)(NG + 1) * 4, 256);
    int4*  csr_pack = (int4*)(wsb + off);  off = align_up(off + (size_t)E * 16, 256);
    float* agg0     = (float*)(wsb + off);
    __half* h2      = (__half*)(wsb + off); off = align_up(off + (size_t)N * EMB * 4, 256);
    float* B        = (float*)(wsb + off);  off = align_up(off + (size_t)N * HID * 4, 256);

    const int* src = edge;
    const int* dst = edge + E;

    // ---- CSR build + boundaries ----
    hipMemsetAsync(deg, 0, (size_t)N * 4, stream);
    k_deg<<<(E + 255) / 256, 256, 0, stream>>>(dst, E, deg);
    k_dinv<<<(N + 255) / 256, 256, 0, stream>>>(deg, dinv, N);
    k_scanA<<<SCAN_T / 256, 256, 0, stream>>>(deg, tsum, N, seg);
    k_scanB<<<1, 256, 0, stream>>>(tsum);
    k_scanC<<<SCAN_T / 256, 256, 0, stream>>>(deg, tsum, rowptr, N, seg, E);
    hipMemsetAsync(deg, 0, (size_t)N * 4, stream);   // reuse as cursor
    k_fill<<<(E + 255) / 256, 256, 0, stream>>>(src, dst, node_ids, dinv, rowptr, deg,
                                                csr_pack, E);
    k_bounds<<<(N + 1 + 255) / 256, 256, 0, stream>>>(batch, gstart, N);

    // ---- layer 1: propagate in embed space, then matmul (bias+relu fused) ----
    k_gather64<<<(N * 64 + 255) / 256, 256, 0, stream>>>(node_ids, embed, csr_pack,
                                                         rowptr, dinv, agg0, N);
    k_mm1<<<(N + MMB - 1) / MMB, 256, 0, stream>>>(agg0, W1, b1, B, N);

    // ---- layer 2: matmul -> fp16 (prescaled by dinv), gather, back into B ----
    k_mm2<<<(N + MMB - 1) / MMB, 256, 0, stream>>>(B, W2, dinv, h2, N);
    k_gather128h<<<(N * 64 + 255) / 256, 256, 0, stream>>>(h2, csr_pack, rowptr, dinv, b2, B, N);

    // ---- fused pool + head ----
    k_pool2<<<(NG * 64 + 255) / 256, 256, 0, stream>>>(B, gstart, Wout, bout, out);
}

// Round 7
// 315.234 us; speedup vs baseline: 1.0356x; 1.0356x over previous
//
#include <hip/hip_runtime.h>
#include <hip/hip_fp16.h>

#define HID 128
#define EMB 64
#define NG  8192
#define NCLS 16
#define SCAN_T 4096
#define MMB 64        // nodes per matmul block

typedef _Float16 f16x8 __attribute__((ext_vector_type(8)));
typedef float    f32x4 __attribute__((ext_vector_type(4)));

// ---------------- degree ----------------
__global__ void k_deg(const int* __restrict__ dst, int E, int* __restrict__ deg) {
    int i = blockIdx.x * 256 + threadIdx.x;
    if (i < E) atomicAdd(&deg[dst[i]], 1);
}

__global__ void k_dinv(const int* __restrict__ deg, float* __restrict__ dinv, int N) {
    int i = blockIdx.x * 256 + threadIdx.x;
    if (i < N) dinv[i] = rsqrtf((float)(deg[i] + 1));  // +1 self-loop
}

// ---------------- exclusive scan of deg -> rowptr ----------------
__global__ void k_scanA(const int* __restrict__ deg, int* __restrict__ tsum, int N, int seg) {
    int t = blockIdx.x * 256 + threadIdx.x;
    int beg = t * seg, end = min(beg + seg, N);
    int s = 0;
    for (int i = beg; i < end; ++i) s += deg[i];
    tsum[t] = s;
}

__global__ void k_scanB(int* __restrict__ tsum) {
    __shared__ int sh[256];
    int tid = threadIdx.x;
    const int PER = SCAN_T / 256;
    int vals[PER];
    int local = 0;
    int base = tid * PER;
#pragma unroll
    for (int i = 0; i < PER; ++i) { vals[i] = tsum[base + i]; local += vals[i]; }
    sh[tid] = local; __syncthreads();
    for (int d = 1; d < 256; d <<= 1) {
        int v = (tid >= d) ? sh[tid - d] : 0;
        __syncthreads();
        sh[tid] += v;
        __syncthreads();
    }
    int off = sh[tid] - local;
#pragma unroll
    for (int i = 0; i < PER; ++i) { int v = vals[i]; tsum[base + i] = off; off += v; }
}

__global__ void k_scanC(const int* __restrict__ deg, const int* __restrict__ tsum,
                        int* __restrict__ rowptr, int N, int seg, int E) {
    int t = blockIdx.x * 256 + threadIdx.x;
    int beg = t * seg, end = min(beg + seg, N);
    int off = tsum[t];
    for (int i = beg; i < end; ++i) { rowptr[i] = off; off += deg[i]; }
    if (t == 0) rowptr[N] = E;
}

// ---------------- CSR fill: packed {src, vid, w_bits, 0} per edge ----------------
__global__ void k_fill(const int* __restrict__ src, const int* __restrict__ dst,
                       const int* __restrict__ ids, const float* __restrict__ dinv,
                       const int* __restrict__ rowptr, int* __restrict__ cursor,
                       int4* __restrict__ csr_pack, int E) {
    int e = blockIdx.x * 256 + threadIdx.x;
    if (e < E) {
        int s = src[e], d = dst[e];
        int pos = atomicAdd(&cursor[d], 1);
        int p = rowptr[d] + pos;
        csr_pack[p] = make_int4(s, ids[s], __float_as_int(dinv[s]), 0);
    }
}

// ---------------- graph segment boundaries from sorted batch ----------------
__global__ void k_bounds(const int* __restrict__ batch, int* __restrict__ gstart, int N) {
    int n = blockIdx.x * 256 + threadIdx.x;
    if (n > N) return;
    int bc = (n < N) ? batch[n] : NG;
    int bp = (n > 0) ? batch[n - 1] : -1;
    for (int g = bp + 1; g <= bc; ++g) gstart[g] = n;
}

// ---------------- W2 transpose -> fp16: wt[c][k] = (half)W2[k][c] ----------------
__global__ void k_wt(const float* __restrict__ W2, __half* __restrict__ wt) {
    int i = blockIdx.x * 256 + threadIdx.x;   // 64 blocks x 256 = 16384
    int c = i >> 7, k = i & 127;
    wt[i] = __float2half(W2[k * HID + c]);
}

// ---------------- layer-1 propagate in 64-dim embed space (L2-resident table) ----
// agg0[d] = dd * ( dd*embed[ids[d]] + sum_e w_e * embed[vid_e] )
__global__ void k_gather64(const int* __restrict__ ids, const float* __restrict__ embed,
                           const int4* __restrict__ csr_pack,
                           const int* __restrict__ rowptr, const float* __restrict__ dinv,
                           float* __restrict__ agg0, int N) {
    int wid = (blockIdx.x * blockDim.x + threadIdx.x) >> 6;  // one wave per node
    if (wid >= N) return;
    int lane = threadIdx.x & 63;
    int d = wid;
    int beg = rowptr[d], end = rowptr[d + 1];
    float dd = dinv[d];
    float acc = embed[(size_t)ids[d] * EMB + lane] * dd;
    int i = beg;
    for (; i + 4 <= end; i += 4) {
        int4 p0 = csr_pack[i], p1 = csr_pack[i + 1], p2 = csr_pack[i + 2], p3 = csr_pack[i + 3];
        float e0 = embed[(size_t)p0.y * EMB + lane];
        float e1 = embed[(size_t)p1.y * EMB + lane];
        float e2 = embed[(size_t)p2.y * EMB + lane];
        float e3 = embed[(size_t)p3.y * EMB + lane];
        acc = fmaf(e0, __int_as_float(p0.z), acc);
        acc = fmaf(e1, __int_as_float(p1.z), acc);
        acc = fmaf(e2, __int_as_float(p2.z), acc);
        acc = fmaf(e3, __int_as_float(p3.z), acc);
    }
    for (; i < end; ++i) {
        int4 p = csr_pack[i];
        acc = fmaf(embed[(size_t)p.y * EMB + lane], __int_as_float(p.z), acc);
    }
    agg0[(size_t)d * EMB + lane] = acc * dd;
}

// ---------------- layer-1 matmul: relu([Nx64]@[64x128] + b1) -> fp16 ----------------
__global__ __launch_bounds__(256) void k_mm1(const float* __restrict__ in,
                                             const float* __restrict__ W1,
                                             const float* __restrict__ b1,
                                             __half* __restrict__ out, int N) {
    __shared__ float rows_t[EMB][64];    // transposed [k][n], 16 KB
    __shared__ float Ws[EMB * HID];      // full W1, 32 KB
    int tid = threadIdx.x;
    int base = blockIdx.x * MMB;
    {
        const float4* wp = (const float4*)W1;
        float4* wsp = (float4*)Ws;
#pragma unroll
        for (int j = 0; j < 8; ++j) wsp[tid + 256 * j] = wp[tid + 256 * j];
    }
    {
        int n = tid & 63;
        int k0 = (tid >> 6) * 16;
        int node = base + n; if (node >= N) node = N - 1;
        const float4* ep = (const float4*)&in[(size_t)node * EMB + k0];
#pragma unroll
        for (int j = 0; j < 4; ++j) {
            float4 v = ep[j];
            int k = k0 + j * 4;
            rows_t[k + 0][n] = v.x; rows_t[k + 1][n] = v.y;
            rows_t[k + 2][n] = v.z; rows_t[k + 3][n] = v.w;
        }
    }
    __syncthreads();
    int n8 = (tid & 7) * 8;
    int c4 = (tid >> 3) * 4;
    float acc[8][4];
#pragma unroll
    for (int i = 0; i < 8; ++i)
#pragma unroll
        for (int j = 0; j < 4; ++j) acc[i][j] = 0.f;
    for (int k = 0; k < EMB; ++k) {
        float4 w = *(const float4*)&Ws[k * HID + c4];
        float4 r0 = *(const float4*)&rows_t[k][n8];
        float4 r1 = *(const float4*)&rows_t[k][n8 + 4];
        float rr[8] = {r0.x, r0.y, r0.z, r0.w, r1.x, r1.y, r1.z, r1.w};
#pragma unroll
        for (int i = 0; i < 8; ++i) {
            acc[i][0] = fmaf(rr[i], w.x, acc[i][0]);
            acc[i][1] = fmaf(rr[i], w.y, acc[i][1]);
            acc[i][2] = fmaf(rr[i], w.z, acc[i][2]);
            acc[i][3] = fmaf(rr[i], w.w, acc[i][3]);
        }
    }
    float4 bb = *(const float4*)&b1[c4];
#pragma unroll
    for (int i = 0; i < 8; ++i) {
        int node = base + n8 + i;
        if (node < N) {
            union { __half h[4]; uint2 u; } pk;
            pk.h[0] = __float2half(fmaxf(acc[i][0] + bb.x, 0.f));
            pk.h[1] = __float2half(fmaxf(acc[i][1] + bb.y, 0.f));
            pk.h[2] = __float2half(fmaxf(acc[i][2] + bb.z, 0.f));
            pk.h[3] = __float2half(fmaxf(acc[i][3] + bb.w, 0.f));
            *(uint2*)&out[(size_t)node * HID + c4] = pk.u;
        }
    }
}

// ---------------- layer-2 matmul via MFMA: h2 = (h1 @ W2) * dinv, fp16 ----------------
// No LDS, no barriers. One wave per 16 nodes; B-frags from L1/L2-resident wt.
__global__ __launch_bounds__(256) void k_mm2_mfma(const __half* __restrict__ h1,
                                                  const __half* __restrict__ wt,
                                                  const float* __restrict__ dinv,
                                                  __half* __restrict__ h2, int N) {
    int tid = threadIdx.x;
    int w = tid >> 6, l = tid & 63;
    int base = blockIdx.x * MMB + w * 16;
    int lrow = l & 15, lkg = l >> 4;
    int arow = base + lrow; if (arow >= N) arow = N - 1;
    // A-frags: lane holds h1[arow][kstep*32 + lkg*8 .. +8]
    const f16x8* ap = (const f16x8*)(h1 + (size_t)arow * HID);
    f16x8 a0 = ap[0 * 4 + lkg], a1 = ap[1 * 4 + lkg];
    f16x8 a2 = ap[2 * 4 + lkg], a3 = ap[3 * 4 + lkg];
    f32x4 acc[8];
#pragma unroll
    for (int ct = 0; ct < 8; ++ct) acc[ct] = (f32x4){0.f, 0.f, 0.f, 0.f};
    const f16x8* wp = (const f16x8*)wt;   // wt[c][k]: row c = 16 f16x8 chunks
#pragma unroll
    for (int ct = 0; ct < 8; ++ct) {
        const f16x8* bp = wp + (ct * 16 + lrow) * 16 + lkg;
        f16x8 b0 = bp[0], b1 = bp[4], b2 = bp[8], b3 = bp[12];
        acc[ct] = __builtin_amdgcn_mfma_f32_16x16x32_f16(a0, b0, acc[ct], 0, 0, 0);
        acc[ct] = __builtin_amdgcn_mfma_f32_16x16x32_f16(a1, b1, acc[ct], 0, 0, 0);
        acc[ct] = __builtin_amdgcn_mfma_f32_16x16x32_f16(a2, b2, acc[ct], 0, 0, 0);
        acc[ct] = __builtin_amdgcn_mfma_f32_16x16x32_f16(a3, b3, acc[ct], 0, 0, 0);
    }
    // C/D layout: col = l&15, row(node) = lkg*4 + r
    int m0 = base + lkg * 4;
    float sc[4];
#pragma unroll
    for (int r = 0; r < 4; ++r) sc[r] = (m0 + r < N) ? dinv[m0 + r] : 0.f;
#pragma unroll
    for (int ct = 0; ct < 8; ++ct) {
        int c = ct * 16 + lrow;
#pragma unroll
        for (int r = 0; r < 4; ++r) {
            int m = m0 + r;
            if (m < N) h2[(size_t)m * HID + c] = __float2half(acc[ct][r] * sc[r]);
        }
    }
}

// ---------------- layer-2 gather: out[d] = relu(dd*(h2[d]+sum h2[s]) + b) ----
__global__ void k_gather128h(const __half* __restrict__ h2, const int4* __restrict__ csr_pack,
                             const int* __restrict__ rowptr, const float* __restrict__ dinv,
                             const float* __restrict__ bias, float* __restrict__ out, int N) {
    int wid = (blockIdx.x * blockDim.x + threadIdx.x) >> 6;  // one wave per node
    if (wid >= N) return;
    int lane = threadIdx.x & 63;
    int d = wid;
    int beg = rowptr[d], end = rowptr[d + 1];
    float dd = dinv[d];
    const __half2* hr = (const __half2*)h2;   // row = 64 half2
    float2 f = __half22float2(hr[(size_t)d * 64 + lane]);
    float ax = f.x, ay = f.y;
    int i = beg;
    for (; i + 4 <= end; i += 4) {
        int s0 = csr_pack[i].x, s1 = csr_pack[i + 1].x;
        int s2 = csr_pack[i + 2].x, s3 = csr_pack[i + 3].x;
        float2 v0 = __half22float2(hr[(size_t)s0 * 64 + lane]);
        float2 v1 = __half22float2(hr[(size_t)s1 * 64 + lane]);
        float2 v2 = __half22float2(hr[(size_t)s2 * 64 + lane]);
        float2 v3 = __half22float2(hr[(size_t)s3 * 64 + lane]);
        ax += (v0.x + v1.x) + (v2.x + v3.x);
        ay += (v0.y + v1.y) + (v2.y + v3.y);
    }
    for (; i < end; ++i) {
        float2 v = __half22float2(hr[(size_t)csr_pack[i].x * 64 + lane]);
        ax += v.x; ay += v.y;
    }
    float2 b = ((const float2*)bias)[lane];
    float2 r;
    r.x = fmaxf(fmaf(ax, dd, b.x), 0.f);
    r.y = fmaxf(fmaf(ay, dd, b.y), 0.f);
    ((float2*)out)[(size_t)d * 64 + lane] = r;
}

// ---------------- fused mean-pool + head: one wave per graph ----------------
__global__ void k_pool2(const float* __restrict__ x, const int* __restrict__ gstart,
                        const float* __restrict__ Wout, const float* __restrict__ bout,
                        float* __restrict__ out) {
    int wid = (blockIdx.x * blockDim.x + threadIdx.x) >> 6;  // graph id
    if (wid >= NG) return;
    int lane = threadIdx.x & 63;
    int beg = gstart[wid], end = gstart[wid + 1];
    const float2* rows = (const float2*)x;
    float sx = 0.f, sy = 0.f;
    for (int n = beg; n < end; ++n) {
        float2 v = rows[(size_t)n * 64 + lane];
        sx += v.x; sy += v.y;
    }
    float inv = (end > beg) ? 1.f / (float)(end - beg) : 1.f;
    sx *= inv; sy *= inv;
    float wo0[NCLS], wo1[NCLS];
    {
        const float4* p0 = (const float4*)&Wout[(size_t)(2 * lane) * NCLS];
        const float4* p1 = (const float4*)&Wout[(size_t)(2 * lane + 1) * NCLS];
#pragma unroll
        for (int j = 0; j < 4; ++j) {
            float4 a = p0[j]; wo0[4*j] = a.x; wo0[4*j+1] = a.y; wo0[4*j+2] = a.z; wo0[4*j+3] = a.w;
            float4 b = p1[j]; wo1[4*j] = b.x; wo1[4*j+1] = b.y; wo1[4*j+2] = b.z; wo1[4*j+3] = b.w;
        }
    }
#pragma unroll
    for (int c = 0; c < NCLS; ++c) {
        float p = fmaf(sx, wo0[c], sy * wo1[c]);
#pragma unroll
        for (int s = 1; s < 64; s <<= 1) p += __shfl_xor(p, s, 64);
        if (lane == c) out[(size_t)wid * NCLS + c] = p + bout[c];
    }
}

static inline size_t align_up(size_t v, size_t a) { return (v + a - 1) & ~(a - 1); }

extern "C" void kernel_launch(void* const* d_in, const int* in_sizes, int n_in,
                              void* d_out, int out_size, void* d_ws, size_t ws_size,
                              hipStream_t stream) {
    const int*   node_ids = (const int*)d_in[0];
    const int*   edge     = (const int*)d_in[1];
    const int*   batch    = (const int*)d_in[2];
    const float* embed    = (const float*)d_in[3];
    const float* W1       = (const float*)d_in[4];
    const float* b1       = (const float*)d_in[5];
    const float* W2       = (const float*)d_in[6];
    const float* b2       = (const float*)d_in[7];
    const float* Wout     = (const float*)d_in[8];
    const float* bout     = (const float*)d_in[9];
    float* out = (float*)d_out;

    const int N = in_sizes[0];
    const int E = in_sizes[1] / 2;
    const int seg = (N + SCAN_T - 1) / SCAN_T;

    // 256B-aligned workspace layout.
    // Overlays: h2 (N*128 fp16) overlays agg0 (N*64 fp32) [agg0 dead after mm1];
    //           C  (N*128 fp32) overlays h1 (N*128 fp16)  [h1 dead after mm2].
    char* wsb = (char*)d_ws;
    size_t off = 0;
    float*  dinv     = (float*)(wsb + off);  off = align_up(off + (size_t)N * 4, 256);
    int*    deg      = (int*)(wsb + off);    off = align_up(off + (size_t)N * 4, 256);
    int*    rowptr   = (int*)(wsb + off);    off = align_up(off + (size_t)(N + 1) * 4, 256);
    int*    tsum     = (int*)(wsb + off);    off = align_up(off + (size_t)SCAN_T * 4, 256);
    int*    gstart   = (int*)(wsb + off);    off = align_up(off + (size_t)(NG + 1) * 4, 256);
    __half* wt       = (__half*)(wsb + off); off = align_up(off + (size_t)HID * HID * 2, 256);
    int4*   csr_pack = (int4*)(wsb + off);   off = align_up(off + (size_t)E * 16, 256);
    float*  agg0     = (float*)(wsb + off);
    __half* h2       = (__half*)(wsb + off); off = align_up(off + (size_t)N * EMB * 4, 256);
    __half* h1       = (__half*)(wsb + off);
    float*  C        = (float*)(wsb + off);  off = align_up(off + (size_t)N * HID * 4, 256);

    const int* src = edge;
    const int* dst = edge + E;

    // ---- CSR build + boundaries + weight transpose ----
    hipMemsetAsync(deg, 0, (size_t)N * 4, stream);
    k_deg<<<(E + 255) / 256, 256, 0, stream>>>(dst, E, deg);
    k_dinv<<<(N + 255) / 256, 256, 0, stream>>>(deg, dinv, N);
    k_scanA<<<SCAN_T / 256, 256, 0, stream>>>(deg, tsum, N, seg);
    k_scanB<<<1, 256, 0, stream>>>(tsum);
    k_scanC<<<SCAN_T / 256, 256, 0, stream>>>(deg, tsum, rowptr, N, seg, E);
    hipMemsetAsync(deg, 0, (size_t)N * 4, stream);   // reuse as cursor
    k_fill<<<(E + 255) / 256, 256, 0, stream>>>(src, dst, node_ids, dinv, rowptr, deg,
                                                csr_pack, E);
    k_bounds<<<(N + 1 + 255) / 256, 256, 0, stream>>>(batch, gstart, N);
    k_wt<<<HID * HID / 256, 256, 0, stream>>>(W2, wt);

    // ---- layer 1: propagate in embed space, then matmul (bias+relu fused) -> fp16 ----
    k_gather64<<<(N * 64 + 255) / 256, 256, 0, stream>>>(node_ids, embed, csr_pack,
                                                         rowptr, dinv, agg0, N);
    k_mm1<<<(N + MMB - 1) / MMB, 256, 0, stream>>>(agg0, W1, b1, h1, N);

    // ---- layer 2: MFMA matmul -> fp16 (prescaled by dinv), then gather -> fp32 C ----
    k_mm2_mfma<<<(N + MMB - 1) / MMB, 256, 0, stream>>>(h1, wt, dinv, h2, N);
    k_gather128h<<<(N * 64 + 255) / 256, 256, 0, stream>>>(h2, csr_pack, rowptr, dinv, b2, C, N);

    // ---- fused pool + head ----
    k_pool2<<<(NG * 64 + 255) / 256, 256, 0, stream>>>(C, gstart, Wout, bout, out);
}

// Round 8
// 313.780 us; speedup vs baseline: 1.0404x; 1.0046x over previous
//
#include <hip/hip_runtime.h>
#include <hip/hip_fp16.h>

#define HID 128
#define EMB 64
#define NG  8192
#define NCLS 16
#define SCAN_T 4096
#define MMB 64        // nodes per matmul block

typedef _Float16 f16x8 __attribute__((ext_vector_type(8)));
typedef float    f32x4 __attribute__((ext_vector_type(4)));

// ---------------- degree ----------------
__global__ void k_deg(const int* __restrict__ dst, int E, int* __restrict__ deg) {
    int i = blockIdx.x * 256 + threadIdx.x;
    if (i < E) atomicAdd(&deg[dst[i]], 1);
}

__global__ void k_dinv(const int* __restrict__ deg, float* __restrict__ dinv, int N) {
    int i = blockIdx.x * 256 + threadIdx.x;
    if (i < N) dinv[i] = rsqrtf((float)(deg[i] + 1));  // +1 self-loop
}

// ---------------- exclusive scan of deg -> rowptr ----------------
__global__ void k_scanA(const int* __restrict__ deg, int* __restrict__ tsum, int N, int seg) {
    int t = blockIdx.x * 256 + threadIdx.x;
    int beg = t * seg, end = min(beg + seg, N);
    int s = 0;
    for (int i = beg; i < end; ++i) s += deg[i];
    tsum[t] = s;
}

__global__ void k_scanB(int* __restrict__ tsum) {
    __shared__ int sh[256];
    int tid = threadIdx.x;
    const int PER = SCAN_T / 256;
    int vals[PER];
    int local = 0;
    int base = tid * PER;
#pragma unroll
    for (int i = 0; i < PER; ++i) { vals[i] = tsum[base + i]; local += vals[i]; }
    sh[tid] = local; __syncthreads();
    for (int d = 1; d < 256; d <<= 1) {
        int v = (tid >= d) ? sh[tid - d] : 0;
        __syncthreads();
        sh[tid] += v;
        __syncthreads();
    }
    int off = sh[tid] - local;
#pragma unroll
    for (int i = 0; i < PER; ++i) { int v = vals[i]; tsum[base + i] = off; off += v; }
}

__global__ void k_scanC(const int* __restrict__ deg, const int* __restrict__ tsum,
                        int* __restrict__ rowptr, int N, int seg, int E) {
    int t = blockIdx.x * 256 + threadIdx.x;
    int beg = t * seg, end = min(beg + seg, N);
    int off = tsum[t];
    for (int i = beg; i < end; ++i) { rowptr[i] = off; off += deg[i]; }
    if (t == 0) rowptr[N] = E;
}

// ---------------- CSR fill: packed {src, vid, w_bits, 0} per edge ----------------
__global__ void k_fill(const int* __restrict__ src, const int* __restrict__ dst,
                       const int* __restrict__ ids, const float* __restrict__ dinv,
                       const int* __restrict__ rowptr, int* __restrict__ cursor,
                       int4* __restrict__ csr_pack, int E) {
    int e = blockIdx.x * 256 + threadIdx.x;
    if (e < E) {
        int s = src[e], d = dst[e];
        int pos = atomicAdd(&cursor[d], 1);
        int p = rowptr[d] + pos;
        csr_pack[p] = make_int4(s, ids[s], __float_as_int(dinv[s]), 0);
    }
}

// ---------------- graph segment boundaries from sorted batch ----------------
__global__ void k_bounds(const int* __restrict__ batch, int* __restrict__ gstart, int N) {
    int n = blockIdx.x * 256 + threadIdx.x;
    if (n > N) return;
    int bc = (n < N) ? batch[n] : NG;
    int bp = (n > 0) ? batch[n - 1] : -1;
    for (int g = bp + 1; g <= bc; ++g) gstart[g] = n;
}

// ---------------- weight transposes -> fp16: wt2[c][k]=W2[k][c], wt1[c][k]=W1[k][c] ----
__global__ void k_wt(const float* __restrict__ W1, const float* __restrict__ W2,
                     __half* __restrict__ wt1, __half* __restrict__ wt2) {
    int i = blockIdx.x * 256 + threadIdx.x;   // 96 blocks x 256 = 24576
    if (i < HID * HID) {
        int c = i >> 7, k = i & 127;
        wt2[i] = __float2half(W2[k * HID + c]);
    } else {
        int j = i - HID * HID;                // EMB*HID entries
        int c = j >> 6, k = j & 63;
        wt1[j] = __float2half(W1[k * HID + c]);
    }
}

// ---------------- layer-1 propagate in 64-dim embed space -> fp16 ----------------
// agg0[d] = dd * ( dd*embed[ids[d]] + sum_e w_e * embed[vid_e] )
__global__ void k_gather64(const int* __restrict__ ids, const float* __restrict__ embed,
                           const int4* __restrict__ csr_pack,
                           const int* __restrict__ rowptr, const float* __restrict__ dinv,
                           __half* __restrict__ agg0h, int N) {
    int wid = (blockIdx.x * blockDim.x + threadIdx.x) >> 6;  // one wave per node
    if (wid >= N) return;
    int lane = threadIdx.x & 63;
    int d = wid;
    int beg = rowptr[d], end = rowptr[d + 1];
    float dd = dinv[d];
    float acc = embed[(size_t)ids[d] * EMB + lane] * dd;
    int i = beg;
    for (; i + 4 <= end; i += 4) {
        int4 p0 = csr_pack[i], p1 = csr_pack[i + 1], p2 = csr_pack[i + 2], p3 = csr_pack[i + 3];
        float e0 = embed[(size_t)p0.y * EMB + lane];
        float e1 = embed[(size_t)p1.y * EMB + lane];
        float e2 = embed[(size_t)p2.y * EMB + lane];
        float e3 = embed[(size_t)p3.y * EMB + lane];
        acc = fmaf(e0, __int_as_float(p0.z), acc);
        acc = fmaf(e1, __int_as_float(p1.z), acc);
        acc = fmaf(e2, __int_as_float(p2.z), acc);
        acc = fmaf(e3, __int_as_float(p3.z), acc);
    }
    for (; i < end; ++i) {
        int4 p = csr_pack[i];
        acc = fmaf(embed[(size_t)p.y * EMB + lane], __int_as_float(p.z), acc);
    }
    agg0h[(size_t)d * EMB + lane] = __float2half(acc * dd);
}

// ---------------- layer-1 matmul via MFMA: h1 = relu(agg0 @ W1 + b1), fp16 ----------
// No LDS, no barriers. One wave per 16 nodes; K=64.
__global__ __launch_bounds__(256) void k_mm1_mfma(const __half* __restrict__ a0h,
                                                  const __half* __restrict__ wt1,
                                                  const float* __restrict__ b1,
                                                  __half* __restrict__ h1, int N) {
    int tid = threadIdx.x;
    int w = tid >> 6, l = tid & 63;
    int base = blockIdx.x * MMB + w * 16;
    int lrow = l & 15, lkg = l >> 4;
    int arow = base + lrow; if (arow >= N) arow = N - 1;
    const f16x8* ap = (const f16x8*)(a0h + (size_t)arow * EMB);   // 8 chunks per row
    f16x8 a0 = ap[lkg], a1 = ap[4 + lkg];
    f32x4 acc[8];
#pragma unroll
    for (int ct = 0; ct < 8; ++ct) acc[ct] = (f32x4){0.f, 0.f, 0.f, 0.f};
    const f16x8* wp = (const f16x8*)wt1;   // wt1[c][k]: row c = 8 f16x8 chunks
#pragma unroll
    for (int ct = 0; ct < 8; ++ct) {
        const f16x8* bp = wp + (ct * 16 + lrow) * 8 + lkg;
        f16x8 b0 = bp[0], b1f = bp[4];
        acc[ct] = __builtin_amdgcn_mfma_f32_16x16x32_f16(a0, b0, acc[ct], 0, 0, 0);
        acc[ct] = __builtin_amdgcn_mfma_f32_16x16x32_f16(a1, b1f, acc[ct], 0, 0, 0);
    }
    int m0 = base + lkg * 4;
#pragma unroll
    for (int ct = 0; ct < 8; ++ct) {
        int c = ct * 16 + lrow;
        float bb = b1[c];
#pragma unroll
        for (int r = 0; r < 4; ++r) {
            int m = m0 + r;
            if (m < N) h1[(size_t)m * HID + c] = __float2half(fmaxf(acc[ct][r] + bb, 0.f));
        }
    }
}

// ---------------- layer-2 matmul via MFMA: h2 = (h1 @ W2) * dinv, fp16 ----------------
__global__ __launch_bounds__(256) void k_mm2_mfma(const __half* __restrict__ h1,
                                                  const __half* __restrict__ wt,
                                                  const float* __restrict__ dinv,
                                                  __half* __restrict__ h2, int N) {
    int tid = threadIdx.x;
    int w = tid >> 6, l = tid & 63;
    int base = blockIdx.x * MMB + w * 16;
    int lrow = l & 15, lkg = l >> 4;
    int arow = base + lrow; if (arow >= N) arow = N - 1;
    const f16x8* ap = (const f16x8*)(h1 + (size_t)arow * HID);
    f16x8 a0 = ap[0 * 4 + lkg], a1 = ap[1 * 4 + lkg];
    f16x8 a2 = ap[2 * 4 + lkg], a3 = ap[3 * 4 + lkg];
    f32x4 acc[8];
#pragma unroll
    for (int ct = 0; ct < 8; ++ct) acc[ct] = (f32x4){0.f, 0.f, 0.f, 0.f};
    const f16x8* wp = (const f16x8*)wt;   // wt[c][k]: row c = 16 f16x8 chunks
#pragma unroll
    for (int ct = 0; ct < 8; ++ct) {
        const f16x8* bp = wp + (ct * 16 + lrow) * 16 + lkg;
        f16x8 b0 = bp[0], b1 = bp[4], b2 = bp[8], b3 = bp[12];
        acc[ct] = __builtin_amdgcn_mfma_f32_16x16x32_f16(a0, b0, acc[ct], 0, 0, 0);
        acc[ct] = __builtin_amdgcn_mfma_f32_16x16x32_f16(a1, b1, acc[ct], 0, 0, 0);
        acc[ct] = __builtin_amdgcn_mfma_f32_16x16x32_f16(a2, b2, acc[ct], 0, 0, 0);
        acc[ct] = __builtin_amdgcn_mfma_f32_16x16x32_f16(a3, b3, acc[ct], 0, 0, 0);
    }
    int m0 = base + lkg * 4;
    float sc[4];
#pragma unroll
    for (int r = 0; r < 4; ++r) sc[r] = (m0 + r < N) ? dinv[m0 + r] : 0.f;
#pragma unroll
    for (int ct = 0; ct < 8; ++ct) {
        int c = ct * 16 + lrow;
#pragma unroll
        for (int r = 0; r < 4; ++r) {
            int m = m0 + r;
            if (m < N) h2[(size_t)m * HID + c] = __float2half(acc[ct][r] * sc[r]);
        }
    }
}

// ---------------- fused: layer-2 gather + bias/relu + mean-pool + head ----------------
// One wave per graph: walk destination nodes, gather rows, pool, 16-class head.
__global__ void k_gp(const __half* __restrict__ h2, const int4* __restrict__ csr_pack,
                     const int* __restrict__ rowptr, const float* __restrict__ dinv,
                     const float* __restrict__ b2, const int* __restrict__ gstart,
                     const float* __restrict__ Wout, const float* __restrict__ bout,
                     float* __restrict__ out) {
    int g = (blockIdx.x * blockDim.x + threadIdx.x) >> 6;  // graph id
    if (g >= NG) return;
    int lane = threadIdx.x & 63;
    int nbeg = gstart[g], nend = gstart[g + 1];
    const __half2* hr = (const __half2*)h2;   // row = 64 half2
    float2 b = ((const float2*)b2)[lane];
    float sx = 0.f, sy = 0.f;
    for (int d = nbeg; d < nend; ++d) {
        int eb = rowptr[d], ee = rowptr[d + 1];
        float dd = dinv[d];
        float2 f = __half22float2(hr[(size_t)d * 64 + lane]);
        float ax = f.x, ay = f.y;
        int i = eb;
        for (; i + 4 <= ee; i += 4) {
            int s0 = csr_pack[i].x, s1 = csr_pack[i + 1].x;
            int s2 = csr_pack[i + 2].x, s3 = csr_pack[i + 3].x;
            float2 v0 = __half22float2(hr[(size_t)s0 * 64 + lane]);
            float2 v1 = __half22float2(hr[(size_t)s1 * 64 + lane]);
            float2 v2 = __half22float2(hr[(size_t)s2 * 64 + lane]);
            float2 v3 = __half22float2(hr[(size_t)s3 * 64 + lane]);
            ax += (v0.x + v1.x) + (v2.x + v3.x);
            ay += (v0.y + v1.y) + (v2.y + v3.y);
        }
        for (; i < ee; ++i) {
            float2 v = __half22float2(hr[(size_t)csr_pack[i].x * 64 + lane]);
            ax += v.x; ay += v.y;
        }
        sx += fmaxf(fmaf(ax, dd, b.x), 0.f);
        sy += fmaxf(fmaf(ay, dd, b.y), 0.f);
    }
    float inv = (nend > nbeg) ? 1.f / (float)(nend - nbeg) : 1.f;
    sx *= inv; sy *= inv;
    // head: lane's two Wout rows are 2*lane and 2*lane+1
    float wo0[NCLS], wo1[NCLS];
    {
        const float4* p0 = (const float4*)&Wout[(size_t)(2 * lane) * NCLS];
        const float4* p1 = (const float4*)&Wout[(size_t)(2 * lane + 1) * NCLS];
#pragma unroll
        for (int j = 0; j < 4; ++j) {
            float4 a = p0[j]; wo0[4*j] = a.x; wo0[4*j+1] = a.y; wo0[4*j+2] = a.z; wo0[4*j+3] = a.w;
            float4 c = p1[j]; wo1[4*j] = c.x; wo1[4*j+1] = c.y; wo1[4*j+2] = c.z; wo1[4*j+3] = c.w;
        }
    }
#pragma unroll
    for (int c = 0; c < NCLS; ++c) {
        float p = fmaf(sx, wo0[c], sy * wo1[c]);
#pragma unroll
        for (int s = 1; s < 64; s <<= 1) p += __shfl_xor(p, s, 64);
        if (lane == c) out[(size_t)g * NCLS + c] = p + bout[c];
    }
}

static inline size_t align_up(size_t v, size_t a) { return (v + a - 1) & ~(a - 1); }

extern "C" void kernel_launch(void* const* d_in, const int* in_sizes, int n_in,
                              void* d_out, int out_size, void* d_ws, size_t ws_size,
                              hipStream_t stream) {
    const int*   node_ids = (const int*)d_in[0];
    const int*   edge     = (const int*)d_in[1];
    const int*   batch    = (const int*)d_in[2];
    const float* embed    = (const float*)d_in[3];
    const float* W1       = (const float*)d_in[4];
    const float* b1       = (const float*)d_in[5];
    const float* W2       = (const float*)d_in[6];
    const float* b2       = (const float*)d_in[7];
    const float* Wout     = (const float*)d_in[8];
    const float* bout     = (const float*)d_in[9];
    float* out = (float*)d_out;

    const int N = in_sizes[0];
    const int E = in_sizes[1] / 2;
    const int seg = (N + SCAN_T - 1) / SCAN_T;

    // 256B-aligned workspace layout (no overlays needed, ~80 MB total)
    char* wsb = (char*)d_ws;
    size_t off = 0;
    float*  dinv     = (float*)(wsb + off);  off = align_up(off + (size_t)N * 4, 256);
    int*    deg      = (int*)(wsb + off);    off = align_up(off + (size_t)N * 4, 256);
    int*    rowptr   = (int*)(wsb + off);    off = align_up(off + (size_t)(N + 1) * 4, 256);
    int*    tsum     = (int*)(wsb + off);    off = align_up(off + (size_t)SCAN_T * 4, 256);
    int*    gstart   = (int*)(wsb + off);    off = align_up(off + (size_t)(NG + 1) * 4, 256);
    __half* wt1      = (__half*)(wsb + off); off = align_up(off + (size_t)EMB * HID * 2, 256);
    __half* wt2      = (__half*)(wsb + off); off = align_up(off + (size_t)HID * HID * 2, 256);
    int4*   csr_pack = (int4*)(wsb + off);   off = align_up(off + (size_t)E * 16, 256);
    __half* agg0h    = (__half*)(wsb + off); off = align_up(off + (size_t)N * EMB * 2, 256);
    __half* h1       = (__half*)(wsb + off); off = align_up(off + (size_t)N * HID * 2, 256);
    __half* h2       = (__half*)(wsb + off); off = align_up(off + (size_t)N * HID * 2, 256);

    const int* src = edge;
    const int* dst = edge + E;

    // ---- CSR build + boundaries + weight transposes ----
    hipMemsetAsync(deg, 0, (size_t)N * 4, stream);
    k_deg<<<(E + 255) / 256, 256, 0, stream>>>(dst, E, deg);
    k_dinv<<<(N + 255) / 256, 256, 0, stream>>>(deg, dinv, N);
    k_scanA<<<SCAN_T / 256, 256, 0, stream>>>(deg, tsum, N, seg);
    k_scanB<<<1, 256, 0, stream>>>(tsum);
    k_scanC<<<SCAN_T / 256, 256, 0, stream>>>(deg, tsum, rowptr, N, seg, E);
    hipMemsetAsync(deg, 0, (size_t)N * 4, stream);   // reuse as cursor
    k_fill<<<(E + 255) / 256, 256, 0, stream>>>(src, dst, node_ids, dinv, rowptr, deg,
                                                csr_pack, E);
    k_bounds<<<(N + 1 + 255) / 256, 256, 0, stream>>>(batch, gstart, N);
    k_wt<<<(HID * HID + EMB * HID) / 256, 256, 0, stream>>>(W1, W2, wt1, wt2);

    // ---- layer 1: propagate in embed space (fp16 out), then MFMA matmul ----
    k_gather64<<<(N * 64 + 255) / 256, 256, 0, stream>>>(node_ids, embed, csr_pack,
                                                         rowptr, dinv, agg0h, N);
    k_mm1_mfma<<<(N + MMB - 1) / MMB, 256, 0, stream>>>(agg0h, wt1, b1, h1, N);

    // ---- layer 2: MFMA matmul -> fp16 (prescaled by dinv) ----
    k_mm2_mfma<<<(N + MMB - 1) / MMB, 256, 0, stream>>>(h1, wt2, dinv, h2, N);

    // ---- fused: gather + bias/relu + mean-pool + head ----
    k_gp<<<(NG * 64 + 255) / 256, 256, 0, stream>>>(h2, csr_pack, rowptr, dinv, b2,
                                                    gstart, Wout, bout, out);
}

// Round 9
// 311.757 us; speedup vs baseline: 1.0472x; 1.0065x over previous
//
#include <hip/hip_runtime.h>
#include <hip/hip_fp16.h>

#define HID 128
#define EMB 64
#define NG  8192
#define NCLS 16
#define SCAN_T 4096
#define MMB 64        // nodes per matmul block

typedef _Float16 f16x8 __attribute__((ext_vector_type(8)));
typedef float    f32x4 __attribute__((ext_vector_type(4)));

// ---------------- degree ----------------
__global__ void k_deg(const int* __restrict__ dst, int E, int* __restrict__ deg) {
    int i = blockIdx.x * 256 + threadIdx.x;
    if (i < E) atomicAdd(&deg[dst[i]], 1);
}

__global__ void k_dinv(const int* __restrict__ deg, float* __restrict__ dinv, int N) {
    int i = blockIdx.x * 256 + threadIdx.x;
    if (i < N) dinv[i] = rsqrtf((float)(deg[i] + 1));  // +1 self-loop
}

// ---------------- exclusive scan of deg -> rowptr ----------------
__global__ void k_scanA(const int* __restrict__ deg, int* __restrict__ tsum, int N, int seg) {
    int t = blockIdx.x * 256 + threadIdx.x;
    int beg = t * seg, end = min(beg + seg, N);
    int s = 0;
    for (int i = beg; i < end; ++i) s += deg[i];
    tsum[t] = s;
}

__global__ void k_scanB(int* __restrict__ tsum) {
    __shared__ int sh[256];
    int tid = threadIdx.x;
    const int PER = SCAN_T / 256;
    int vals[PER];
    int local = 0;
    int base = tid * PER;
#pragma unroll
    for (int i = 0; i < PER; ++i) { vals[i] = tsum[base + i]; local += vals[i]; }
    sh[tid] = local; __syncthreads();
    for (int d = 1; d < 256; d <<= 1) {
        int v = (tid >= d) ? sh[tid - d] : 0;
        __syncthreads();
        sh[tid] += v;
        __syncthreads();
    }
    int off = sh[tid] - local;
#pragma unroll
    for (int i = 0; i < PER; ++i) { int v = vals[i]; tsum[base + i] = off; off += v; }
}

__global__ void k_scanC(const int* __restrict__ deg, const int* __restrict__ tsum,
                        int* __restrict__ rowptr, int N, int seg, int E) {
    int t = blockIdx.x * 256 + threadIdx.x;
    int beg = t * seg, end = min(beg + seg, N);
    int off = tsum[t];
    for (int i = beg; i < end; ++i) { rowptr[i] = off; off += deg[i]; }
    if (t == 0) rowptr[N] = E;
}

// ---------------- CSR fill: packed {src, vid, w_bits, 0} per edge ----------------
__global__ void k_fill(const int* __restrict__ src, const int* __restrict__ dst,
                       const int* __restrict__ ids, const float* __restrict__ dinv,
                       const int* __restrict__ rowptr, int* __restrict__ cursor,
                       int4* __restrict__ csr_pack, int E) {
    int e = blockIdx.x * 256 + threadIdx.x;
    if (e < E) {
        int s = src[e], d = dst[e];
        int pos = atomicAdd(&cursor[d], 1);
        int p = rowptr[d] + pos;
        csr_pack[p] = make_int4(s, ids[s], __float_as_int(dinv[s]), 0);
    }
}

// ---------------- graph segment boundaries from sorted batch ----------------
__global__ void k_bounds(const int* __restrict__ batch, int* __restrict__ gstart, int N) {
    int n = blockIdx.x * 256 + threadIdx.x;
    if (n > N) return;
    int bc = (n < N) ? batch[n] : NG;
    int bp = (n > 0) ? batch[n - 1] : -1;
    for (int g = bp + 1; g <= bc; ++g) gstart[g] = n;
}

// ---------------- W2 transpose -> fp16: wt2[c][k] = (half)W2[k][c] ----------------
__global__ void k_wt(const float* __restrict__ W2, __half* __restrict__ wt2) {
    int i = blockIdx.x * 256 + threadIdx.x;
    int c = i >> 7, k = i & 127;
    wt2[i] = __float2half(W2[k * HID + c]);
}

// ---------------- XW = embed @ W1 -> fp16 [V x 128] (one wave per vocab row) ------
__global__ void k_xw(const float* __restrict__ embed, const float* __restrict__ W1,
                     __half* __restrict__ xw, int V) {
    int v = (blockIdx.x * blockDim.x + threadIdx.x) >> 6;
    if (v >= V) return;
    int lane = threadIdx.x & 63;
    float ev = embed[(size_t)v * EMB + lane];
    float a0 = 0.f, a1 = 0.f;
#pragma unroll
    for (int k = 0; k < EMB; ++k) {
        float e = __shfl(ev, k, 64);
        float2 w = *(const float2*)&W1[k * HID + 2 * lane];
        a0 = fmaf(e, w.x, a0);
        a1 = fmaf(e, w.y, a1);
    }
    ((__half2*)xw)[(size_t)v * 64 + lane] = __floats2half2_rn(a0, a1);
}

// ---------------- layer-1: gather in 128-d XW space + bias + relu -> h1 fp16 ------
// h1[d] = relu( dd*( dd*XW[ids[d]] + sum_e w_e*XW[vid_e] ) + b1 )
__global__ void k_gather1(const int* __restrict__ ids, const __half* __restrict__ xw,
                          const int4* __restrict__ csr_pack, const int* __restrict__ rowptr,
                          const float* __restrict__ dinv, const float* __restrict__ b1,
                          __half* __restrict__ h1, int N) {
    int d = (blockIdx.x * blockDim.x + threadIdx.x) >> 6;  // one wave per node
    if (d >= N) return;
    int lane = threadIdx.x & 63;
    int beg = rowptr[d], end = rowptr[d + 1];
    float dd = dinv[d];
    const __half2* xr = (const __half2*)xw;
    float2 sf = __half22float2(xr[(size_t)ids[d] * 64 + lane]);
    float ax = dd * sf.x, ay = dd * sf.y;
    int i = beg;
    for (; i + 8 <= end; i += 8) {
        int4 p[8];
#pragma unroll
        for (int j = 0; j < 8; ++j) p[j] = csr_pack[i + j];
        float2 v[8];
#pragma unroll
        for (int j = 0; j < 8; ++j) v[j] = __half22float2(xr[(size_t)p[j].y * 64 + lane]);
#pragma unroll
        for (int j = 0; j < 8; ++j) {
            float w = __int_as_float(p[j].z);
            ax = fmaf(v[j].x, w, ax);
            ay = fmaf(v[j].y, w, ay);
        }
    }
    for (; i < end; ++i) {
        int4 p = csr_pack[i];
        float w = __int_as_float(p.z);
        float2 v = __half22float2(xr[(size_t)p.y * 64 + lane]);
        ax = fmaf(v.x, w, ax);
        ay = fmaf(v.y, w, ay);
    }
    float2 b = ((const float2*)b1)[lane];
    ((__half2*)h1)[(size_t)d * 64 + lane] =
        __floats2half2_rn(fmaxf(fmaf(ax, dd, b.x), 0.f), fmaxf(fmaf(ay, dd, b.y), 0.f));
}

// ---------------- layer-2 matmul via MFMA: h2 = (h1 @ W2) * dinv, fp16 ----------------
__global__ __launch_bounds__(256) void k_mm2_mfma(const __half* __restrict__ h1,
                                                  const __half* __restrict__ wt,
                                                  const float* __restrict__ dinv,
                                                  __half* __restrict__ h2, int N) {
    int tid = threadIdx.x;
    int w = tid >> 6, l = tid & 63;
    int base = blockIdx.x * MMB + w * 16;
    int lrow = l & 15, lkg = l >> 4;
    int arow = base + lrow; if (arow >= N) arow = N - 1;
    const f16x8* ap = (const f16x8*)(h1 + (size_t)arow * HID);
    f16x8 a0 = ap[0 * 4 + lkg], a1 = ap[1 * 4 + lkg];
    f16x8 a2 = ap[2 * 4 + lkg], a3 = ap[3 * 4 + lkg];
    f32x4 acc[8];
#pragma unroll
    for (int ct = 0; ct < 8; ++ct) acc[ct] = (f32x4){0.f, 0.f, 0.f, 0.f};
    const f16x8* wp = (const f16x8*)wt;   // wt[c][k]: row c = 16 f16x8 chunks
#pragma unroll
    for (int ct = 0; ct < 8; ++ct) {
        const f16x8* bp = wp + (ct * 16 + lrow) * 16 + lkg;
        f16x8 b0 = bp[0], b1 = bp[4], b2 = bp[8], b3 = bp[12];
        acc[ct] = __builtin_amdgcn_mfma_f32_16x16x32_f16(a0, b0, acc[ct], 0, 0, 0);
        acc[ct] = __builtin_amdgcn_mfma_f32_16x16x32_f16(a1, b1, acc[ct], 0, 0, 0);
        acc[ct] = __builtin_amdgcn_mfma_f32_16x16x32_f16(a2, b2, acc[ct], 0, 0, 0);
        acc[ct] = __builtin_amdgcn_mfma_f32_16x16x32_f16(a3, b3, acc[ct], 0, 0, 0);
    }
    int m0 = base + lkg * 4;
    float sc[4];
#pragma unroll
    for (int r = 0; r < 4; ++r) sc[r] = (m0 + r < N) ? dinv[m0 + r] : 0.f;
#pragma unroll
    for (int ct = 0; ct < 8; ++ct) {
        int c = ct * 16 + lrow;
#pragma unroll
        for (int r = 0; r < 4; ++r) {
            int m = m0 + r;
            if (m < N) h2[(size_t)m * HID + c] = __float2half(acc[ct][r] * sc[r]);
        }
    }
}

// ---------------- layer-2 gather: x2[d] = relu(dd*(h2[d]+sum h2[s]) + b2), fp16 -----
__global__ void k_gather2(const __half* __restrict__ h2, const int4* __restrict__ csr_pack,
                          const int* __restrict__ rowptr, const float* __restrict__ dinv,
                          const float* __restrict__ b2, __half* __restrict__ x2, int N) {
    int d = (blockIdx.x * blockDim.x + threadIdx.x) >> 6;  // one wave per node
    if (d >= N) return;
    int lane = threadIdx.x & 63;
    int beg = rowptr[d], end = rowptr[d + 1];
    float dd = dinv[d];
    const __half2* hr = (const __half2*)h2;   // row = 64 half2
    float2 f = __half22float2(hr[(size_t)d * 64 + lane]);
    float ax = f.x, ay = f.y;
    int i = beg;
    for (; i + 8 <= end; i += 8) {
        int s[8];
#pragma unroll
        for (int j = 0; j < 8; ++j) s[j] = csr_pack[i + j].x;
        float2 v[8];
#pragma unroll
        for (int j = 0; j < 8; ++j) v[j] = __half22float2(hr[(size_t)s[j] * 64 + lane]);
#pragma unroll
        for (int j = 0; j < 8; ++j) { ax += v[j].x; ay += v[j].y; }
    }
    for (; i < end; ++i) {
        float2 v = __half22float2(hr[(size_t)csr_pack[i].x * 64 + lane]);
        ax += v.x; ay += v.y;
    }
    float2 b = ((const float2*)b2)[lane];
    ((__half2*)x2)[(size_t)d * 64 + lane] =
        __floats2half2_rn(fmaxf(fmaf(ax, dd, b.x), 0.f), fmaxf(fmaf(ay, dd, b.y), 0.f));
}

// ---------------- mean-pool + head: one wave per graph, contiguous fp16 rows --------
__global__ void k_poolhead(const __half* __restrict__ x2, const int* __restrict__ gstart,
                           const float* __restrict__ Wout, const float* __restrict__ bout,
                           float* __restrict__ out) {
    int g = (blockIdx.x * blockDim.x + threadIdx.x) >> 6;  // graph id
    if (g >= NG) return;
    int lane = threadIdx.x & 63;
    int beg = gstart[g], end = gstart[g + 1];
    const __half2* rows = (const __half2*)x2;
    float sx = 0.f, sy = 0.f;
    for (int n = beg; n < end; ++n) {
        float2 v = __half22float2(rows[(size_t)n * 64 + lane]);
        sx += v.x; sy += v.y;
    }
    float inv = (end > beg) ? 1.f / (float)(end - beg) : 1.f;
    sx *= inv; sy *= inv;
    // head: lane's two Wout rows are 2*lane and 2*lane+1
    float wo0[NCLS], wo1[NCLS];
    {
        const float4* p0 = (const float4*)&Wout[(size_t)(2 * lane) * NCLS];
        const float4* p1 = (const float4*)&Wout[(size_t)(2 * lane + 1) * NCLS];
#pragma unroll
        for (int j = 0; j < 4; ++j) {
            float4 a = p0[j]; wo0[4*j] = a.x; wo0[4*j+1] = a.y; wo0[4*j+2] = a.z; wo0[4*j+3] = a.w;
            float4 c = p1[j]; wo1[4*j] = c.x; wo1[4*j+1] = c.y; wo1[4*j+2] = c.z; wo1[4*j+3] = c.w;
        }
    }
#pragma unroll
    for (int c = 0; c < NCLS; ++c) {
        float p = fmaf(sx, wo0[c], sy * wo1[c]);
#pragma unroll
        for (int s = 1; s < 64; s <<= 1) p += __shfl_xor(p, s, 64);
        if (lane == c) out[(size_t)g * NCLS + c] = p + bout[c];
    }
}

static inline size_t align_up(size_t v, size_t a) { return (v + a - 1) & ~(a - 1); }

extern "C" void kernel_launch(void* const* d_in, const int* in_sizes, int n_in,
                              void* d_out, int out_size, void* d_ws, size_t ws_size,
                              hipStream_t stream) {
    const int*   node_ids = (const int*)d_in[0];
    const int*   edge     = (const int*)d_in[1];
    const int*   batch    = (const int*)d_in[2];
    const float* embed    = (const float*)d_in[3];
    const float* W1       = (const float*)d_in[4];
    const float* b1       = (const float*)d_in[5];
    const float* W2       = (const float*)d_in[6];
    const float* b2       = (const float*)d_in[7];
    const float* Wout     = (const float*)d_in[8];
    const float* bout     = (const float*)d_in[9];
    float* out = (float*)d_out;

    const int N = in_sizes[0];
    const int E = in_sizes[1] / 2;
    const int V = in_sizes[3] / EMB;
    const int seg = (N + SCAN_T - 1) / SCAN_T;

    // 256B-aligned workspace layout (~95 MB)
    char* wsb = (char*)d_ws;
    size_t off = 0;
    float*  dinv     = (float*)(wsb + off);  off = align_up(off + (size_t)N * 4, 256);
    int*    deg      = (int*)(wsb + off);    off = align_up(off + (size_t)N * 4, 256);
    int*    rowptr   = (int*)(wsb + off);    off = align_up(off + (size_t)(N + 1) * 4, 256);
    int*    tsum     = (int*)(wsb + off);    off = align_up(off + (size_t)SCAN_T * 4, 256);
    int*    gstart   = (int*)(wsb + off);    off = align_up(off + (size_t)(NG + 1) * 4, 256);
    __half* wt2      = (__half*)(wsb + off); off = align_up(off + (size_t)HID * HID * 2, 256);
    __half* xw       = (__half*)(wsb + off); off = align_up(off + (size_t)V * HID * 2, 256);
    int4*   csr_pack = (int4*)(wsb + off);   off = align_up(off + (size_t)E * 16, 256);
    __half* h1       = (__half*)(wsb + off); off = align_up(off + (size_t)N * HID * 2, 256);
    __half* h2       = (__half*)(wsb + off); off = align_up(off + (size_t)N * HID * 2, 256);
    __half* x2       = (__half*)(wsb + off); off = align_up(off + (size_t)N * HID * 2, 256);

    const int* src = edge;
    const int* dst = edge + E;

    // ---- CSR build + boundaries + weight prep ----
    hipMemsetAsync(deg, 0, (size_t)N * 4, stream);
    k_deg<<<(E + 255) / 256, 256, 0, stream>>>(dst, E, deg);
    k_dinv<<<(N + 255) / 256, 256, 0, stream>>>(deg, dinv, N);
    k_scanA<<<SCAN_T / 256, 256, 0, stream>>>(deg, tsum, N, seg);
    k_scanB<<<1, 256, 0, stream>>>(tsum);
    k_scanC<<<SCAN_T / 256, 256, 0, stream>>>(deg, tsum, rowptr, N, seg, E);
    hipMemsetAsync(deg, 0, (size_t)N * 4, stream);   // reuse as cursor
    k_fill<<<(E + 255) / 256, 256, 0, stream>>>(src, dst, node_ids, dinv, rowptr, deg,
                                                csr_pack, E);
    k_bounds<<<(N + 1 + 255) / 256, 256, 0, stream>>>(batch, gstart, N);
    k_wt<<<HID * HID / 256, 256, 0, stream>>>(W2, wt2);
    k_xw<<<(V * 64 + 255) / 256, 256, 0, stream>>>(embed, W1, xw, V);

    // ---- layer 1: gather in 128-d XW space (bias+relu fused) -> h1 fp16 ----
    k_gather1<<<(N * 64 + 255) / 256, 256, 0, stream>>>(node_ids, xw, csr_pack, rowptr,
                                                        dinv, b1, h1, N);

    // ---- layer 2: MFMA matmul -> fp16 (prescaled by dinv), then gather -> x2 fp16 ----
    k_mm2_mfma<<<(N + MMB - 1) / MMB, 256, 0, stream>>>(h1, wt2, dinv, h2, N);
    k_gather2<<<(N * 64 + 255) / 256, 256, 0, stream>>>(h2, csr_pack, rowptr, dinv, b2, x2, N);

    // ---- mean-pool + head ----
    k_poolhead<<<(NG * 64 + 255) / 256, 256, 0, stream>>>(x2, gstart, Wout, bout, out);
}

// Round 10
// 290.368 us; speedup vs baseline: 1.1243x; 1.0737x over previous
//
#include <hip/hip_runtime.h>
#include <hip/hip_fp16.h>

#define HID 128
#define EMB 64
#define NG  8192
#define NCLS 16
#define SCAN_T 4096
#define MMB 64        // nodes per matmul block

typedef _Float16 f16x8 __attribute__((ext_vector_type(8)));
typedef float    f32x4 __attribute__((ext_vector_type(4)));

__device__ __forceinline__ float4 cvt4(uint2 r) {
    float2 a = __half22float2(*(const __half2*)&r.x);
    float2 b = __half22float2(*(const __half2*)&r.y);
    return make_float4(a.x, a.y, b.x, b.y);
}

// ---------------- degree ----------------
__global__ void k_deg(const int* __restrict__ dst, int E, int* __restrict__ deg) {
    int i = blockIdx.x * 256 + threadIdx.x;
    if (i < E) atomicAdd(&deg[dst[i]], 1);
}

__global__ void k_dinv(const int* __restrict__ deg, float* __restrict__ dinv, int N) {
    int i = blockIdx.x * 256 + threadIdx.x;
    if (i < N) dinv[i] = rsqrtf((float)(deg[i] + 1));  // +1 self-loop
}

// ---------------- exclusive scan of deg -> rowptr ----------------
__global__ void k_scanA(const int* __restrict__ deg, int* __restrict__ tsum, int N, int seg) {
    int t = blockIdx.x * 256 + threadIdx.x;
    int beg = t * seg, end = min(beg + seg, N);
    int s = 0;
    for (int i = beg; i < end; ++i) s += deg[i];
    tsum[t] = s;
}

__global__ void k_scanB(int* __restrict__ tsum) {
    __shared__ int sh[256];
    int tid = threadIdx.x;
    const int PER = SCAN_T / 256;
    int vals[PER];
    int local = 0;
    int base = tid * PER;
#pragma unroll
    for (int i = 0; i < PER; ++i) { vals[i] = tsum[base + i]; local += vals[i]; }
    sh[tid] = local; __syncthreads();
    for (int d = 1; d < 256; d <<= 1) {
        int v = (tid >= d) ? sh[tid - d] : 0;
        __syncthreads();
        sh[tid] += v;
        __syncthreads();
    }
    int off = sh[tid] - local;
#pragma unroll
    for (int i = 0; i < PER; ++i) { int v = vals[i]; tsum[base + i] = off; off += v; }
}

__global__ void k_scanC(const int* __restrict__ deg, const int* __restrict__ tsum,
                        int* __restrict__ rowptr, int N, int seg, int E) {
    int t = blockIdx.x * 256 + threadIdx.x;
    int beg = t * seg, end = min(beg + seg, N);
    int off = tsum[t];
    for (int i = beg; i < end; ++i) { rowptr[i] = off; off += deg[i]; }
    if (t == 0) rowptr[N] = E;
}

// ---------------- CSR fill: packed {src, vid, w_bits, 0} per edge ----------------
__global__ void k_fill(const int* __restrict__ src, const int* __restrict__ dst,
                       const int* __restrict__ ids, const float* __restrict__ dinv,
                       const int* __restrict__ rowptr, int* __restrict__ cursor,
                       int4* __restrict__ csr_pack, int E) {
    int e = blockIdx.x * 256 + threadIdx.x;
    if (e < E) {
        int s = src[e], d = dst[e];
        int pos = atomicAdd(&cursor[d], 1);
        int p = rowptr[d] + pos;
        csr_pack[p] = make_int4(s, ids[s], __float_as_int(dinv[s]), 0);
    }
}

// ---------------- graph segment boundaries from sorted batch ----------------
__global__ void k_bounds(const int* __restrict__ batch, int* __restrict__ gstart, int N) {
    int n = blockIdx.x * 256 + threadIdx.x;
    if (n > N) return;
    int bc = (n < N) ? batch[n] : NG;
    int bp = (n > 0) ? batch[n - 1] : -1;
    for (int g = bp + 1; g <= bc; ++g) gstart[g] = n;
}

// ---------------- W2 transpose -> fp16: wt2[c][k] = (half)W2[k][c] ----------------
__global__ void k_wt(const float* __restrict__ W2, __half* __restrict__ wt2) {
    int i = blockIdx.x * 256 + threadIdx.x;
    int c = i >> 7, k = i & 127;
    wt2[i] = __float2half(W2[k * HID + c]);
}

// ---------------- XW = embed @ W1 -> fp16 [V x 128] (one wave per vocab row) ------
__global__ void k_xw(const float* __restrict__ embed, const float* __restrict__ W1,
                     __half* __restrict__ xw, int V) {
    int v = (blockIdx.x * blockDim.x + threadIdx.x) >> 6;
    if (v >= V) return;
    int lane = threadIdx.x & 63;
    float ev = embed[(size_t)v * EMB + lane];
    float a0 = 0.f, a1 = 0.f;
#pragma unroll
    for (int k = 0; k < EMB; ++k) {
        float e = __shfl(ev, k, 64);
        float2 w = *(const float2*)&W1[k * HID + 2 * lane];
        a0 = fmaf(e, w.x, a0);
        a1 = fmaf(e, w.y, a1);
    }
    ((__half2*)xw)[(size_t)v * 64 + lane] = __floats2half2_rn(a0, a1);
}

// ---------------- layer-1: paired gather in 128-d XW space + bias + relu -> h1 ----
// h1[d] = relu( dd*( dd*XW[ids[d]] + sum_e w_e*XW[vid_e] ) + b1 )
// Two edges per wave: half-wave eh=lane>>5 handles edge i+2j+eh, 8 B/lane rows.
__global__ void k_gather1(const int* __restrict__ ids, const __half* __restrict__ xw,
                          const int4* __restrict__ csr_pack, const int* __restrict__ rowptr,
                          const float* __restrict__ dinv, const float* __restrict__ b1,
                          __half* __restrict__ h1, int N) {
    int d = (blockIdx.x * blockDim.x + threadIdx.x) >> 6;  // one wave per node
    if (d >= N) return;
    int lane = threadIdx.x & 63;
    int eh = lane >> 5, c = lane & 31;        // edge-parity, 8B-chunk index
    int beg = rowptr[d], end = rowptr[d + 1];
    float dd = dinv[d];
    float4 acc = make_float4(0.f, 0.f, 0.f, 0.f);
    if (eh == 0) {                            // self term, group 0 only
        uint2 r = ((const uint2*)(xw + (size_t)ids[d] * HID))[c];
        float4 f = cvt4(r);
        acc.x = dd * f.x; acc.y = dd * f.y; acc.z = dd * f.z; acc.w = dd * f.w;
    }
    int i = beg;
    for (; i + 8 <= end; i += 8) {            // 4 pairs = 8 edges in flight
        int4 p[4];
#pragma unroll
        for (int j = 0; j < 4; ++j) p[j] = csr_pack[i + 2 * j + eh];
        uint2 r[4];
#pragma unroll
        for (int j = 0; j < 4; ++j) r[j] = ((const uint2*)(xw + (size_t)p[j].y * HID))[c];
#pragma unroll
        for (int j = 0; j < 4; ++j) {
            float w = __int_as_float(p[j].z);
            float4 f = cvt4(r[j]);
            acc.x = fmaf(f.x, w, acc.x); acc.y = fmaf(f.y, w, acc.y);
            acc.z = fmaf(f.z, w, acc.z); acc.w = fmaf(f.w, w, acc.w);
        }
    }
    for (; i + 2 <= end; i += 2) {            // pair remainder
        int4 p = csr_pack[i + eh];
        uint2 r = ((const uint2*)(xw + (size_t)p.y * HID))[c];
        float w = __int_as_float(p.z);
        float4 f = cvt4(r);
        acc.x = fmaf(f.x, w, acc.x); acc.y = fmaf(f.y, w, acc.y);
        acc.z = fmaf(f.z, w, acc.z); acc.w = fmaf(f.w, w, acc.w);
    }
    if (i < end && eh == 0) {                 // odd last edge, group 0 only
        int4 p = csr_pack[i];
        uint2 r = ((const uint2*)(xw + (size_t)p.y * HID))[c];
        float w = __int_as_float(p.z);
        float4 f = cvt4(r);
        acc.x = fmaf(f.x, w, acc.x); acc.y = fmaf(f.y, w, acc.y);
        acc.z = fmaf(f.z, w, acc.z); acc.w = fmaf(f.w, w, acc.w);
    }
    // combine the two half-wave partials
    acc.x += __shfl_xor(acc.x, 32, 64);
    acc.y += __shfl_xor(acc.y, 32, 64);
    acc.z += __shfl_xor(acc.z, 32, 64);
    acc.w += __shfl_xor(acc.w, 32, 64);
    float4 bb = *(const float4*)&b1[c * 4];
    if (eh == 0) {
        __half2 lo = __floats2half2_rn(fmaxf(fmaf(acc.x, dd, bb.x), 0.f),
                                       fmaxf(fmaf(acc.y, dd, bb.y), 0.f));
        __half2 hi = __floats2half2_rn(fmaxf(fmaf(acc.z, dd, bb.z), 0.f),
                                       fmaxf(fmaf(acc.w, dd, bb.w), 0.f));
        uint2 pk = make_uint2(*(unsigned*)&lo, *(unsigned*)&hi);
        ((uint2*)(h1 + (size_t)d * HID))[c] = pk;
    }
}

// ---------------- layer-2 matmul via MFMA: h2 = (h1 @ W2) * dinv, fp16 ----------------
__global__ __launch_bounds__(256) void k_mm2_mfma(const __half* __restrict__ h1,
                                                  const __half* __restrict__ wt,
                                                  const float* __restrict__ dinv,
                                                  __half* __restrict__ h2, int N) {
    int tid = threadIdx.x;
    int w = tid >> 6, l = tid & 63;
    int base = blockIdx.x * MMB + w * 16;
    int lrow = l & 15, lkg = l >> 4;
    int arow = base + lrow; if (arow >= N) arow = N - 1;
    const f16x8* ap = (const f16x8*)(h1 + (size_t)arow * HID);
    f16x8 a0 = ap[0 * 4 + lkg], a1 = ap[1 * 4 + lkg];
    f16x8 a2 = ap[2 * 4 + lkg], a3 = ap[3 * 4 + lkg];
    f32x4 acc[8];
#pragma unroll
    for (int ct = 0; ct < 8; ++ct) acc[ct] = (f32x4){0.f, 0.f, 0.f, 0.f};
    const f16x8* wp = (const f16x8*)wt;   // wt[c][k]: row c = 16 f16x8 chunks
#pragma unroll
    for (int ct = 0; ct < 8; ++ct) {
        const f16x8* bp = wp + (ct * 16 + lrow) * 16 + lkg;
        f16x8 b0 = bp[0], b1 = bp[4], b2 = bp[8], b3 = bp[12];
        acc[ct] = __builtin_amdgcn_mfma_f32_16x16x32_f16(a0, b0, acc[ct], 0, 0, 0);
        acc[ct] = __builtin_amdgcn_mfma_f32_16x16x32_f16(a1, b1, acc[ct], 0, 0, 0);
        acc[ct] = __builtin_amdgcn_mfma_f32_16x16x32_f16(a2, b2, acc[ct], 0, 0, 0);
        acc[ct] = __builtin_amdgcn_mfma_f32_16x16x32_f16(a3, b3, acc[ct], 0, 0, 0);
    }
    int m0 = base + lkg * 4;
    float sc[4];
#pragma unroll
    for (int r = 0; r < 4; ++r) sc[r] = (m0 + r < N) ? dinv[m0 + r] : 0.f;
#pragma unroll
    for (int ct = 0; ct < 8; ++ct) {
        int c = ct * 16 + lrow;
#pragma unroll
        for (int r = 0; r < 4; ++r) {
            int m = m0 + r;
            if (m < N) h2[(size_t)m * HID + c] = __float2half(acc[ct][r] * sc[r]);
        }
    }
}

// ---------------- layer-2 paired gather: x2[d] = relu(dd*(h2[d]+sum h2[s]) + b2) ----
__global__ void k_gather2(const __half* __restrict__ h2, const int4* __restrict__ csr_pack,
                          const int* __restrict__ rowptr, const float* __restrict__ dinv,
                          const float* __restrict__ b2, __half* __restrict__ x2, int N) {
    int d = (blockIdx.x * blockDim.x + threadIdx.x) >> 6;  // one wave per node
    if (d >= N) return;
    int lane = threadIdx.x & 63;
    int eh = lane >> 5, c = lane & 31;
    int beg = rowptr[d], end = rowptr[d + 1];
    float dd = dinv[d];
    float4 acc = make_float4(0.f, 0.f, 0.f, 0.f);
    if (eh == 0) {                            // self term (weight 1, prescaled)
        uint2 r = ((const uint2*)(h2 + (size_t)d * HID))[c];
        float4 f = cvt4(r);
        acc.x = f.x; acc.y = f.y; acc.z = f.z; acc.w = f.w;
    }
    int i = beg;
    for (; i + 8 <= end; i += 8) {
        int s[4];
#pragma unroll
        for (int j = 0; j < 4; ++j) s[j] = csr_pack[i + 2 * j + eh].x;
        uint2 r[4];
#pragma unroll
        for (int j = 0; j < 4; ++j) r[j] = ((const uint2*)(h2 + (size_t)s[j] * HID))[c];
#pragma unroll
        for (int j = 0; j < 4; ++j) {
            float4 f = cvt4(r[j]);
            acc.x += f.x; acc.y += f.y; acc.z += f.z; acc.w += f.w;
        }
    }
    for (; i + 2 <= end; i += 2) {
        int s = csr_pack[i + eh].x;
        uint2 r = ((const uint2*)(h2 + (size_t)s * HID))[c];
        float4 f = cvt4(r);
        acc.x += f.x; acc.y += f.y; acc.z += f.z; acc.w += f.w;
    }
    if (i < end && eh == 0) {
        int s = csr_pack[i].x;
        uint2 r = ((const uint2*)(h2 + (size_t)s * HID))[c];
        float4 f = cvt4(r);
        acc.x += f.x; acc.y += f.y; acc.z += f.z; acc.w += f.w;
    }
    acc.x += __shfl_xor(acc.x, 32, 64);
    acc.y += __shfl_xor(acc.y, 32, 64);
    acc.z += __shfl_xor(acc.z, 32, 64);
    acc.w += __shfl_xor(acc.w, 32, 64);
    float4 bb = *(const float4*)&b2[c * 4];
    if (eh == 0) {
        __half2 lo = __floats2half2_rn(fmaxf(fmaf(acc.x, dd, bb.x), 0.f),
                                       fmaxf(fmaf(acc.y, dd, bb.y), 0.f));
        __half2 hi = __floats2half2_rn(fmaxf(fmaf(acc.z, dd, bb.z), 0.f),
                                       fmaxf(fmaf(acc.w, dd, bb.w), 0.f));
        uint2 pk = make_uint2(*(unsigned*)&lo, *(unsigned*)&hi);
        ((uint2*)(x2 + (size_t)d * HID))[c] = pk;
    }
}

// ---------------- mean-pool + head: one wave per graph, contiguous fp16 rows --------
__global__ void k_poolhead(const __half* __restrict__ x2, const int* __restrict__ gstart,
                           const float* __restrict__ Wout, const float* __restrict__ bout,
                           float* __restrict__ out) {
    int g = (blockIdx.x * blockDim.x + threadIdx.x) >> 6;  // graph id
    if (g >= NG) return;
    int lane = threadIdx.x & 63;
    int beg = gstart[g], end = gstart[g + 1];
    const __half2* rows = (const __half2*)x2;
    float sx = 0.f, sy = 0.f;
    for (int n = beg; n < end; ++n) {
        float2 v = __half22float2(rows[(size_t)n * 64 + lane]);
        sx += v.x; sy += v.y;
    }
    float inv = (end > beg) ? 1.f / (float)(end - beg) : 1.f;
    sx *= inv; sy *= inv;
    float wo0[NCLS], wo1[NCLS];
    {
        const float4* p0 = (const float4*)&Wout[(size_t)(2 * lane) * NCLS];
        const float4* p1 = (const float4*)&Wout[(size_t)(2 * lane + 1) * NCLS];
#pragma unroll
        for (int j = 0; j < 4; ++j) {
            float4 a = p0[j]; wo0[4*j] = a.x; wo0[4*j+1] = a.y; wo0[4*j+2] = a.z; wo0[4*j+3] = a.w;
            float4 c = p1[j]; wo1[4*j] = c.x; wo1[4*j+1] = c.y; wo1[4*j+2] = c.z; wo1[4*j+3] = c.w;
        }
    }
#pragma unroll
    for (int c = 0; c < NCLS; ++c) {
        float p = fmaf(sx, wo0[c], sy * wo1[c]);
#pragma unroll
        for (int s = 1; s < 64; s <<= 1) p += __shfl_xor(p, s, 64);
        if (lane == c) out[(size_t)g * NCLS + c] = p + bout[c];
    }
}

static inline size_t align_up(size_t v, size_t a) { return (v + a - 1) & ~(a - 1); }

extern "C" void kernel_launch(void* const* d_in, const int* in_sizes, int n_in,
                              void* d_out, int out_size, void* d_ws, size_t ws_size,
                              hipStream_t stream) {
    const int*   node_ids = (const int*)d_in[0];
    const int*   edge     = (const int*)d_in[1];
    const int*   batch    = (const int*)d_in[2];
    const float* embed    = (const float*)d_in[3];
    const float* W1       = (const float*)d_in[4];
    const float* b1       = (const float*)d_in[5];
    const float* W2       = (const float*)d_in[6];
    const float* b2       = (const float*)d_in[7];
    const float* Wout     = (const float*)d_in[8];
    const float* bout     = (const float*)d_in[9];
    float* out = (float*)d_out;

    const int N = in_sizes[0];
    const int E = in_sizes[1] / 2;
    const int V = in_sizes[3] / EMB;
    const int seg = (N + SCAN_T - 1) / SCAN_T;

    // 256B-aligned workspace layout (~95 MB)
    char* wsb = (char*)d_ws;
    size_t off = 0;
    float*  dinv     = (float*)(wsb + off);  off = align_up(off + (size_t)N * 4, 256);
    int*    deg      = (int*)(wsb + off);    off = align_up(off + (size_t)N * 4, 256);
    int*    rowptr   = (int*)(wsb + off);    off = align_up(off + (size_t)(N + 1) * 4, 256);
    int*    tsum     = (int*)(wsb + off);    off = align_up(off + (size_t)SCAN_T * 4, 256);
    int*    gstart   = (int*)(wsb + off);    off = align_up(off + (size_t)(NG + 1) * 4, 256);
    __half* wt2      = (__half*)(wsb + off); off = align_up(off + (size_t)HID * HID * 2, 256);
    __half* xw       = (__half*)(wsb + off); off = align_up(off + (size_t)V * HID * 2, 256);
    int4*   csr_pack = (int4*)(wsb + off);   off = align_up(off + (size_t)E * 16, 256);
    __half* h1       = (__half*)(wsb + off); off = align_up(off + (size_t)N * HID * 2, 256);
    __half* h2       = (__half*)(wsb + off); off = align_up(off + (size_t)N * HID * 2, 256);
    __half* x2       = (__half*)(wsb + off); off = align_up(off + (size_t)N * HID * 2, 256);

    const int* src = edge;
    const int* dst = edge + E;

    // ---- CSR build + boundaries + weight prep ----
    hipMemsetAsync(deg, 0, (size_t)N * 4, stream);
    k_deg<<<(E + 255) / 256, 256, 0, stream>>>(dst, E, deg);
    k_dinv<<<(N + 255) / 256, 256, 0, stream>>>(deg, dinv, N);
    k_scanA<<<SCAN_T / 256, 256, 0, stream>>>(deg, tsum, N, seg);
    k_scanB<<<1, 256, 0, stream>>>(tsum);
    k_scanC<<<SCAN_T / 256, 256, 0, stream>>>(deg, tsum, rowptr, N, seg, E);
    hipMemsetAsync(deg, 0, (size_t)N * 4, stream);   // reuse as cursor
    k_fill<<<(E + 255) / 256, 256, 0, stream>>>(src, dst, node_ids, dinv, rowptr, deg,
                                                csr_pack, E);
    k_bounds<<<(N + 1 + 255) / 256, 256, 0, stream>>>(batch, gstart, N);
    k_wt<<<HID * HID / 256, 256, 0, stream>>>(W2, wt2);
    k_xw<<<(V * 64 + 255) / 256, 256, 0, stream>>>(embed, W1, xw, V);

    // ---- layer 1: paired gather in 128-d XW space (bias+relu fused) -> h1 fp16 ----
    k_gather1<<<(N * 64 + 255) / 256, 256, 0, stream>>>(node_ids, xw, csr_pack, rowptr,
                                                        dinv, b1, h1, N);

    // ---- layer 2: MFMA matmul -> fp16 (prescaled by dinv), then paired gather ----
    k_mm2_mfma<<<(N + MMB - 1) / MMB, 256, 0, stream>>>(h1, wt2, dinv, h2, N);
    k_gather2<<<(N * 64 + 255) / 256, 256, 0, stream>>>(h2, csr_pack, rowptr, dinv, b2, x2, N);

    // ---- mean-pool + head ----
    k_poolhead<<<(NG * 64 + 255) / 256, 256, 0, stream>>>(x2, gstart, Wout, bout, out);
}

// Round 11
// 279.821 us; speedup vs baseline: 1.1667x; 1.0377x over previous
//
#include <hip/hip_runtime.h>
#include <hip/hip_fp16.h>

#define HID 128
#define EMB 64
#define NG  8192
#define NCLS 16
#define SCAN_T 4096
#define MMB 64        // nodes per matmul block

typedef _Float16 f16x8 __attribute__((ext_vector_type(8)));
typedef float    f32x4 __attribute__((ext_vector_type(4)));

__device__ __forceinline__ void acc8(float* a, uint4 r) {
    float2 f0 = __half22float2(*(const __half2*)&r.x);
    float2 f1 = __half22float2(*(const __half2*)&r.y);
    float2 f2 = __half22float2(*(const __half2*)&r.z);
    float2 f3 = __half22float2(*(const __half2*)&r.w);
    a[0] += f0.x; a[1] += f0.y; a[2] += f1.x; a[3] += f1.y;
    a[4] += f2.x; a[5] += f2.y; a[6] += f3.x; a[7] += f3.y;
}

__device__ __forceinline__ void fma8(float* a, uint4 r, float w) {
    float2 f0 = __half22float2(*(const __half2*)&r.x);
    float2 f1 = __half22float2(*(const __half2*)&r.y);
    float2 f2 = __half22float2(*(const __half2*)&r.z);
    float2 f3 = __half22float2(*(const __half2*)&r.w);
    a[0] = fmaf(f0.x, w, a[0]); a[1] = fmaf(f0.y, w, a[1]);
    a[2] = fmaf(f1.x, w, a[2]); a[3] = fmaf(f1.y, w, a[3]);
    a[4] = fmaf(f2.x, w, a[4]); a[5] = fmaf(f2.y, w, a[5]);
    a[6] = fmaf(f3.x, w, a[6]); a[7] = fmaf(f3.y, w, a[7]);
}

// ---------------- degree ----------------
__global__ void k_deg(const int* __restrict__ dst, int E, int* __restrict__ deg) {
    int i = blockIdx.x * 256 + threadIdx.x;
    if (i < E) atomicAdd(&deg[dst[i]], 1);
}

// ---------------- exclusive scan of deg -> rowptr (+ dinv fused in C) ----------------
__global__ void k_scanA(const int* __restrict__ deg, int* __restrict__ tsum, int N, int seg) {
    int t = blockIdx.x * 256 + threadIdx.x;
    int beg = t * seg, end = min(beg + seg, N);
    int s = 0;
    for (int i = beg; i < end; ++i) s += deg[i];
    tsum[t] = s;
}

__global__ void k_scanB(int* __restrict__ tsum) {
    __shared__ int sh[256];
    int tid = threadIdx.x;
    const int PER = SCAN_T / 256;
    int vals[PER];
    int local = 0;
    int base = tid * PER;
#pragma unroll
    for (int i = 0; i < PER; ++i) { vals[i] = tsum[base + i]; local += vals[i]; }
    sh[tid] = local; __syncthreads();
    for (int d = 1; d < 256; d <<= 1) {
        int v = (tid >= d) ? sh[tid - d] : 0;
        __syncthreads();
        sh[tid] += v;
        __syncthreads();
    }
    int off = sh[tid] - local;
#pragma unroll
    for (int i = 0; i < PER; ++i) { int v = vals[i]; tsum[base + i] = off; off += v; }
}

__global__ void k_scanC(const int* __restrict__ deg, const int* __restrict__ tsum,
                        int* __restrict__ rowptr, float* __restrict__ dinv,
                        int N, int seg, int E) {
    int t = blockIdx.x * 256 + threadIdx.x;
    int beg = t * seg, end = min(beg + seg, N);
    int off = tsum[t];
    for (int i = beg; i < end; ++i) {
        int dg = deg[i];
        rowptr[i] = off; off += dg;
        dinv[i] = rsqrtf((float)(dg + 1));   // +1 self-loop
    }
    if (t == 0) rowptr[N] = E;
}

// ---------------- CSR fill: packed {src, vid, w_bits, 0} per edge ----------------
__global__ void k_fill(const int* __restrict__ src, const int* __restrict__ dst,
                       const int* __restrict__ ids, const float* __restrict__ dinv,
                       const int* __restrict__ rowptr, int* __restrict__ cursor,
                       int4* __restrict__ csr_pack, int E) {
    int e = blockIdx.x * 256 + threadIdx.x;
    if (e < E) {
        int s = src[e], d = dst[e];
        int pos = atomicAdd(&cursor[d], 1);
        int p = rowptr[d] + pos;
        csr_pack[p] = make_int4(s, ids[s], __float_as_int(dinv[s]), 0);
    }
}

// ---------------- graph segment boundaries from sorted batch ----------------
__global__ void k_bounds(const int* __restrict__ batch, int* __restrict__ gstart, int N) {
    int n = blockIdx.x * 256 + threadIdx.x;
    if (n > N) return;
    int bc = (n < N) ? batch[n] : NG;
    int bp = (n > 0) ? batch[n - 1] : -1;
    for (int g = bp + 1; g <= bc; ++g) gstart[g] = n;
}

// ---------------- fused weight prep: XW = embed@W1 -> fp16; wt2 = W2^T fp16 ---------
// Blocks [0, xwBlocks): one wave per vocab row. Blocks [xwBlocks, +64): wt2 transpose.
__global__ void k_prep(const float* __restrict__ embed, const float* __restrict__ W1,
                       const float* __restrict__ W2, __half* __restrict__ xw,
                       __half* __restrict__ wt2, int V, int xwBlocks) {
    if ((int)blockIdx.x < xwBlocks) {
        int v = (blockIdx.x * 256 + threadIdx.x) >> 6;
        if (v >= V) return;
        int lane = threadIdx.x & 63;
        float ev = embed[(size_t)v * EMB + lane];
        float a0 = 0.f, a1 = 0.f;
#pragma unroll
        for (int k = 0; k < EMB; ++k) {
            float e = __shfl(ev, k, 64);
            float2 w = *(const float2*)&W1[k * HID + 2 * lane];
            a0 = fmaf(e, w.x, a0);
            a1 = fmaf(e, w.y, a1);
        }
        ((__half2*)xw)[(size_t)v * 64 + lane] = __floats2half2_rn(a0, a1);
    } else {
        int i = (blockIdx.x - xwBlocks) * 256 + threadIdx.x;   // 64 blocks: 16384
        int c = i >> 7, k = i & 127;
        wt2[i] = __float2half(W2[k * HID + c]);
    }
}

// ---------------- layer-1: quarter-wave gather in XW space + bias + relu -> h1 ------
// h1[d] = relu( dd*( dd*XW[ids[d]] + sum_e w_e*XW[vid_e] ) + b1 )
// 4 edge-groups of 16 lanes; each group loads a full 256 B row as uint4.
__global__ void k_gather1(const int* __restrict__ ids, const __half* __restrict__ xw,
                          const int4* __restrict__ csr_pack, const int* __restrict__ rowptr,
                          const float* __restrict__ dinv, const float* __restrict__ bias,
                          __half* __restrict__ h1, int N) {
    int d = (blockIdx.x * blockDim.x + threadIdx.x) >> 6;  // one wave per node
    if (d >= N) return;
    int lane = threadIdx.x & 63;
    int eg = lane >> 4, c = lane & 15;        // edge-group, 16B-chunk index
    int beg = rowptr[d], end = rowptr[d + 1];
    float dd = dinv[d];
    float a[8] = {0.f, 0.f, 0.f, 0.f, 0.f, 0.f, 0.f, 0.f};
    if (eg == 0) {                            // self term
        uint4 r = ((const uint4*)(xw + (size_t)ids[d] * HID))[c];
        fma8(a, r, dd);
    }
    int i = beg;
    for (; i + 16 <= end; i += 16) {          // 4 edges/group, 4 row loads in flight
        int4 p[4]; uint4 r[4];
#pragma unroll
        for (int j = 0; j < 4; ++j) p[j] = csr_pack[i + 4 * j + eg];
#pragma unroll
        for (int j = 0; j < 4; ++j) r[j] = ((const uint4*)(xw + (size_t)p[j].y * HID))[c];
#pragma unroll
        for (int j = 0; j < 4; ++j) fma8(a, r[j], __int_as_float(p[j].z));
    }
    for (; i + 8 <= end; i += 8) {
        int4 p[2]; uint4 r[2];
#pragma unroll
        for (int j = 0; j < 2; ++j) p[j] = csr_pack[i + 4 * j + eg];
#pragma unroll
        for (int j = 0; j < 2; ++j) r[j] = ((const uint4*)(xw + (size_t)p[j].y * HID))[c];
#pragma unroll
        for (int j = 0; j < 2; ++j) fma8(a, r[j], __int_as_float(p[j].z));
    }
    for (; i + 4 <= end; i += 4) {
        int4 p = csr_pack[i + eg];
        uint4 r = ((const uint4*)(xw + (size_t)p.y * HID))[c];
        fma8(a, r, __int_as_float(p.z));
    }
    int rem = end - i;
    if (eg < rem) {
        int4 p = csr_pack[i + eg];
        uint4 r = ((const uint4*)(xw + (size_t)p.y * HID))[c];
        fma8(a, r, __int_as_float(p.z));
    }
#pragma unroll
    for (int k = 0; k < 8; ++k) {
        a[k] += __shfl_xor(a[k], 32, 64);
        a[k] += __shfl_xor(a[k], 16, 64);
    }
    if (eg == 0) {
        float4 bl = *(const float4*)&bias[c * 8];
        float4 bh = *(const float4*)&bias[c * 8 + 4];
        __half2 h0 = __floats2half2_rn(fmaxf(fmaf(a[0], dd, bl.x), 0.f),
                                       fmaxf(fmaf(a[1], dd, bl.y), 0.f));
        __half2 h1v = __floats2half2_rn(fmaxf(fmaf(a[2], dd, bl.z), 0.f),
                                        fmaxf(fmaf(a[3], dd, bl.w), 0.f));
        __half2 h2v = __floats2half2_rn(fmaxf(fmaf(a[4], dd, bh.x), 0.f),
                                        fmaxf(fmaf(a[5], dd, bh.y), 0.f));
        __half2 h3 = __floats2half2_rn(fmaxf(fmaf(a[6], dd, bh.z), 0.f),
                                       fmaxf(fmaf(a[7], dd, bh.w), 0.f));
        uint4 pk = make_uint4(*(unsigned*)&h0, *(unsigned*)&h1v,
                              *(unsigned*)&h2v, *(unsigned*)&h3);
        ((uint4*)(h1 + (size_t)d * HID))[c] = pk;
    }
}

// ---------------- layer-2 matmul via MFMA: h2 = (h1 @ W2) * dinv, fp16 ----------------
__global__ __launch_bounds__(256) void k_mm2_mfma(const __half* __restrict__ h1,
                                                  const __half* __restrict__ wt,
                                                  const float* __restrict__ dinv,
                                                  __half* __restrict__ h2, int N) {
    int tid = threadIdx.x;
    int w = tid >> 6, l = tid & 63;
    int base = blockIdx.x * MMB + w * 16;
    int lrow = l & 15, lkg = l >> 4;
    int arow = base + lrow; if (arow >= N) arow = N - 1;
    const f16x8* ap = (const f16x8*)(h1 + (size_t)arow * HID);
    f16x8 a0 = ap[0 * 4 + lkg], a1 = ap[1 * 4 + lkg];
    f16x8 a2 = ap[2 * 4 + lkg], a3 = ap[3 * 4 + lkg];
    f32x4 acc[8];
#pragma unroll
    for (int ct = 0; ct < 8; ++ct) acc[ct] = (f32x4){0.f, 0.f, 0.f, 0.f};
    const f16x8* wp = (const f16x8*)wt;   // wt[c][k]: row c = 16 f16x8 chunks
#pragma unroll
    for (int ct = 0; ct < 8; ++ct) {
        const f16x8* bp = wp + (ct * 16 + lrow) * 16 + lkg;
        f16x8 b0 = bp[0], b1 = bp[4], b2 = bp[8], b3 = bp[12];
        acc[ct] = __builtin_amdgcn_mfma_f32_16x16x32_f16(a0, b0, acc[ct], 0, 0, 0);
        acc[ct] = __builtin_amdgcn_mfma_f32_16x16x32_f16(a1, b1, acc[ct], 0, 0, 0);
        acc[ct] = __builtin_amdgcn_mfma_f32_16x16x32_f16(a2, b2, acc[ct], 0, 0, 0);
        acc[ct] = __builtin_amdgcn_mfma_f32_16x16x32_f16(a3, b3, acc[ct], 0, 0, 0);
    }
    int m0 = base + lkg * 4;
    float sc[4];
#pragma unroll
    for (int r = 0; r < 4; ++r) sc[r] = (m0 + r < N) ? dinv[m0 + r] : 0.f;
#pragma unroll
    for (int ct = 0; ct < 8; ++ct) {
        int c = ct * 16 + lrow;
#pragma unroll
        for (int r = 0; r < 4; ++r) {
            int m = m0 + r;
            if (m < N) h2[(size_t)m * HID + c] = __float2half(acc[ct][r] * sc[r]);
        }
    }
}

// ---------------- layer-2 quarter-wave gather: x2[d]=relu(dd*(h2[d]+sum h2[s])+b2) --
__global__ void k_gather2(const __half* __restrict__ h2, const int4* __restrict__ csr_pack,
                          const int* __restrict__ rowptr, const float* __restrict__ dinv,
                          const float* __restrict__ bias, __half* __restrict__ x2, int N) {
    int d = (blockIdx.x * blockDim.x + threadIdx.x) >> 6;  // one wave per node
    if (d >= N) return;
    int lane = threadIdx.x & 63;
    int eg = lane >> 4, c = lane & 15;
    int beg = rowptr[d], end = rowptr[d + 1];
    float dd = dinv[d];
    float a[8] = {0.f, 0.f, 0.f, 0.f, 0.f, 0.f, 0.f, 0.f};
    if (eg == 0) {                            // self term (prescaled by dinv already)
        uint4 r = ((const uint4*)(h2 + (size_t)d * HID))[c];
        acc8(a, r);
    }
    int i = beg;
    for (; i + 16 <= end; i += 16) {
        int s[4]; uint4 r[4];
#pragma unroll
        for (int j = 0; j < 4; ++j) s[j] = csr_pack[i + 4 * j + eg].x;
#pragma unroll
        for (int j = 0; j < 4; ++j) r[j] = ((const uint4*)(h2 + (size_t)s[j] * HID))[c];
#pragma unroll
        for (int j = 0; j < 4; ++j) acc8(a, r[j]);
    }
    for (; i + 8 <= end; i += 8) {
        int s[2]; uint4 r[2];
#pragma unroll
        for (int j = 0; j < 2; ++j) s[j] = csr_pack[i + 4 * j + eg].x;
#pragma unroll
        for (int j = 0; j < 2; ++j) r[j] = ((const uint4*)(h2 + (size_t)s[j] * HID))[c];
#pragma unroll
        for (int j = 0; j < 2; ++j) acc8(a, r[j]);
    }
    for (; i + 4 <= end; i += 4) {
        int s = csr_pack[i + eg].x;
        uint4 r = ((const uint4*)(h2 + (size_t)s * HID))[c];
        acc8(a, r);
    }
    int rem = end - i;
    if (eg < rem) {
        int s = csr_pack[i + eg].x;
        uint4 r = ((const uint4*)(h2 + (size_t)s * HID))[c];
        acc8(a, r);
    }
#pragma unroll
    for (int k = 0; k < 8; ++k) {
        a[k] += __shfl_xor(a[k], 32, 64);
        a[k] += __shfl_xor(a[k], 16, 64);
    }
    if (eg == 0) {
        float4 bl = *(const float4*)&bias[c * 8];
        float4 bh = *(const float4*)&bias[c * 8 + 4];
        __half2 h0 = __floats2half2_rn(fmaxf(fmaf(a[0], dd, bl.x), 0.f),
                                       fmaxf(fmaf(a[1], dd, bl.y), 0.f));
        __half2 h1v = __floats2half2_rn(fmaxf(fmaf(a[2], dd, bl.z), 0.f),
                                        fmaxf(fmaf(a[3], dd, bl.w), 0.f));
        __half2 h2v = __floats2half2_rn(fmaxf(fmaf(a[4], dd, bh.x), 0.f),
                                        fmaxf(fmaf(a[5], dd, bh.y), 0.f));
        __half2 h3 = __floats2half2_rn(fmaxf(fmaf(a[6], dd, bh.z), 0.f),
                                       fmaxf(fmaf(a[7], dd, bh.w), 0.f));
        uint4 pk = make_uint4(*(unsigned*)&h0, *(unsigned*)&h1v,
                              *(unsigned*)&h2v, *(unsigned*)&h3);
        ((uint4*)(x2 + (size_t)d * HID))[c] = pk;
    }
}

// ---------------- mean-pool + head: one wave per graph, contiguous fp16 rows --------
__global__ void k_poolhead(const __half* __restrict__ x2, const int* __restrict__ gstart,
                           const float* __restrict__ Wout, const float* __restrict__ bout,
                           float* __restrict__ out) {
    int g = (blockIdx.x * blockDim.x + threadIdx.x) >> 6;  // graph id
    if (g >= NG) return;
    int lane = threadIdx.x & 63;
    int beg = gstart[g], end = gstart[g + 1];
    const __half2* rows = (const __half2*)x2;
    float sx = 0.f, sy = 0.f;
    for (int n = beg; n < end; ++n) {
        float2 v = __half22float2(rows[(size_t)n * 64 + lane]);
        sx += v.x; sy += v.y;
    }
    float inv = (end > beg) ? 1.f / (float)(end - beg) : 1.f;
    sx *= inv; sy *= inv;
    float wo0[NCLS], wo1[NCLS];
    {
        const float4* p0 = (const float4*)&Wout[(size_t)(2 * lane) * NCLS];
        const float4* p1 = (const float4*)&Wout[(size_t)(2 * lane + 1) * NCLS];
#pragma unroll
        for (int j = 0; j < 4; ++j) {
            float4 a = p0[j]; wo0[4*j] = a.x; wo0[4*j+1] = a.y; wo0[4*j+2] = a.z; wo0[4*j+3] = a.w;
            float4 c = p1[j]; wo1[4*j] = c.x; wo1[4*j+1] = c.y; wo1[4*j+2] = c.z; wo1[4*j+3] = c.w;
        }
    }
#pragma unroll
    for (int c = 0; c < NCLS; ++c) {
        float p = fmaf(sx, wo0[c], sy * wo1[c]);
#pragma unroll
        for (int s = 1; s < 64; s <<= 1) p += __shfl_xor(p, s, 64);
        if (lane == c) out[(size_t)g * NCLS + c] = p + bout[c];
    }
}

static inline size_t align_up(size_t v, size_t a) { return (v + a - 1) & ~(a - 1); }

extern "C" void kernel_launch(void* const* d_in, const int* in_sizes, int n_in,
                              void* d_out, int out_size, void* d_ws, size_t ws_size,
                              hipStream_t stream) {
    const int*   node_ids = (const int*)d_in[0];
    const int*   edge     = (const int*)d_in[1];
    const int*   batch    = (const int*)d_in[2];
    const float* embed    = (const float*)d_in[3];
    const float* W1       = (const float*)d_in[4];
    const float* b1       = (const float*)d_in[5];
    const float* W2       = (const float*)d_in[6];
    const float* b2       = (const float*)d_in[7];
    const float* Wout     = (const float*)d_in[8];
    const float* bout     = (const float*)d_in[9];
    float* out = (float*)d_out;

    const int N = in_sizes[0];
    const int E = in_sizes[1] / 2;
    const int V = in_sizes[3] / EMB;
    const int seg = (N + SCAN_T - 1) / SCAN_T;

    // 256B-aligned workspace layout (~95 MB)
    char* wsb = (char*)d_ws;
    size_t off = 0;
    float*  dinv     = (float*)(wsb + off);  off = align_up(off + (size_t)N * 4, 256);
    int*    deg      = (int*)(wsb + off);    off = align_up(off + (size_t)N * 4, 256);
    int*    rowptr   = (int*)(wsb + off);    off = align_up(off + (size_t)(N + 1) * 4, 256);
    int*    tsum     = (int*)(wsb + off);    off = align_up(off + (size_t)SCAN_T * 4, 256);
    int*    gstart   = (int*)(wsb + off);    off = align_up(off + (size_t)(NG + 1) * 4, 256);
    __half* wt2      = (__half*)(wsb + off); off = align_up(off + (size_t)HID * HID * 2, 256);
    __half* xw       = (__half*)(wsb + off); off = align_up(off + (size_t)V * HID * 2, 256);
    int4*   csr_pack = (int4*)(wsb + off);   off = align_up(off + (size_t)E * 16, 256);
    __half* h1       = (__half*)(wsb + off); off = align_up(off + (size_t)N * HID * 2, 256);
    __half* h2       = (__half*)(wsb + off); off = align_up(off + (size_t)N * HID * 2, 256);
    __half* x2       = (__half*)(wsb + off); off = align_up(off + (size_t)N * HID * 2, 256);

    const int* src = edge;
    const int* dst = edge + E;

    // ---- CSR build + boundaries + weight prep ----
    hipMemsetAsync(deg, 0, (size_t)N * 4, stream);
    k_deg<<<(E + 255) / 256, 256, 0, stream>>>(dst, E, deg);
    k_scanA<<<SCAN_T / 256, 256, 0, stream>>>(deg, tsum, N, seg);
    k_scanB<<<1, 256, 0, stream>>>(tsum);
    k_scanC<<<SCAN_T / 256, 256, 0, stream>>>(deg, tsum, rowptr, dinv, N, seg, E);
    hipMemsetAsync(deg, 0, (size_t)N * 4, stream);   // reuse as cursor
    k_fill<<<(E + 255) / 256, 256, 0, stream>>>(src, dst, node_ids, dinv, rowptr, deg,
                                                csr_pack, E);
    k_bounds<<<(N + 1 + 255) / 256, 256, 0, stream>>>(batch, gstart, N);
    {
        int xwBlocks = (V * 64 + 255) / 256;
        k_prep<<<xwBlocks + 64, 256, 0, stream>>>(embed, W1, W2, xw, wt2, V, xwBlocks);
    }

    // ---- layer 1: quarter-wave gather in XW space (bias+relu fused) -> h1 fp16 ----
    k_gather1<<<(N * 64 + 255) / 256, 256, 0, stream>>>(node_ids, xw, csr_pack, rowptr,
                                                        dinv, b1, h1, N);

    // ---- layer 2: MFMA matmul -> fp16 (prescaled by dinv), then quarter-wave gather ----
    k_mm2_mfma<<<(N + MMB - 1) / MMB, 256, 0, stream>>>(h1, wt2, dinv, h2, N);
    k_gather2<<<(N * 64 + 255) / 256, 256, 0, stream>>>(h2, csr_pack, rowptr, dinv, b2, x2, N);

    // ---- mean-pool + head ----
    k_poolhead<<<(NG * 64 + 255) / 256, 256, 0, stream>>>(x2, gstart, Wout, bout, out);
}

// Round 12
// 279.637 us; speedup vs baseline: 1.1674x; 1.0007x over previous
//
#include <hip/hip_runtime.h>
#include <hip/hip_fp16.h>

#define HID 128
#define EMB 64
#define NG  8192
#define NCLS 16
#define SCAN_T 4096
#define MMB 64        // nodes per matmul block
#define SRCBITS 17    // N=100000 < 2^17; VOCAB=5000 < 2^13

typedef _Float16 f16x8 __attribute__((ext_vector_type(8)));
typedef float    f32x4 __attribute__((ext_vector_type(4)));

__device__ __forceinline__ void acc8(float* a, uint4 r) {
    float2 f0 = __half22float2(*(const __half2*)&r.x);
    float2 f1 = __half22float2(*(const __half2*)&r.y);
    float2 f2 = __half22float2(*(const __half2*)&r.z);
    float2 f3 = __half22float2(*(const __half2*)&r.w);
    a[0] += f0.x; a[1] += f0.y; a[2] += f1.x; a[3] += f1.y;
    a[4] += f2.x; a[5] += f2.y; a[6] += f3.x; a[7] += f3.y;
}

__device__ __forceinline__ void fma8(float* a, uint4 r, float w) {
    float2 f0 = __half22float2(*(const __half2*)&r.x);
    float2 f1 = __half22float2(*(const __half2*)&r.y);
    float2 f2 = __half22float2(*(const __half2*)&r.z);
    float2 f3 = __half22float2(*(const __half2*)&r.w);
    a[0] = fmaf(f0.x, w, a[0]); a[1] = fmaf(f0.y, w, a[1]);
    a[2] = fmaf(f1.x, w, a[2]); a[3] = fmaf(f1.y, w, a[3]);
    a[4] = fmaf(f2.x, w, a[4]); a[5] = fmaf(f2.y, w, a[5]);
    a[6] = fmaf(f3.x, w, a[6]); a[7] = fmaf(f3.y, w, a[7]);
}

// ---------------- degree ----------------
__global__ void k_deg(const int* __restrict__ dst, int E, int* __restrict__ deg) {
    int i = blockIdx.x * 256 + threadIdx.x;
    if (i < E) atomicAdd(&deg[dst[i]], 1);
}

// ---------------- exclusive scan of deg -> rowptr (+ dinv fused in C) ----------------
__global__ void k_scanA(const int* __restrict__ deg, int* __restrict__ tsum, int N, int seg) {
    int t = blockIdx.x * 256 + threadIdx.x;
    int beg = t * seg, end = min(beg + seg, N);
    int s = 0;
    for (int i = beg; i < end; ++i) s += deg[i];
    tsum[t] = s;
}

__global__ void k_scanB(int* __restrict__ tsum) {
    __shared__ int sh[256];
    int tid = threadIdx.x;
    const int PER = SCAN_T / 256;
    int vals[PER];
    int local = 0;
    int base = tid * PER;
#pragma unroll
    for (int i = 0; i < PER; ++i) { vals[i] = tsum[base + i]; local += vals[i]; }
    sh[tid] = local; __syncthreads();
    for (int d = 1; d < 256; d <<= 1) {
        int v = (tid >= d) ? sh[tid - d] : 0;
        __syncthreads();
        sh[tid] += v;
        __syncthreads();
    }
    int off = sh[tid] - local;
#pragma unroll
    for (int i = 0; i < PER; ++i) { int v = vals[i]; tsum[base + i] = off; off += v; }
}

__global__ void k_scanC(const int* __restrict__ deg, const int* __restrict__ tsum,
                        int* __restrict__ rowptr, float* __restrict__ dinv,
                        int N, int seg, int E) {
    int t = blockIdx.x * 256 + threadIdx.x;
    int beg = t * seg, end = min(beg + seg, N);
    int off = tsum[t];
    for (int i = beg; i < end; ++i) {
        int dg = deg[i];
        rowptr[i] = off; off += dg;
        dinv[i] = rsqrtf((float)(dg + 1));   // +1 self-loop
    }
    if (t == 0) rowptr[N] = E;
}

// ---------------- CSR fill: ONE packed u32 per edge: (vid<<17)|src ----------------
__global__ void k_fill(const int* __restrict__ src, const int* __restrict__ dst,
                       const int* __restrict__ ids, const int* __restrict__ rowptr,
                       int* __restrict__ cursor, unsigned* __restrict__ csr32, int E) {
    int e = blockIdx.x * 256 + threadIdx.x;
    if (e < E) {
        int s = src[e], d = dst[e];
        int pos = atomicAdd(&cursor[d], 1);
        csr32[rowptr[d] + pos] = ((unsigned)ids[s] << SRCBITS) | (unsigned)s;
    }
}

// ---------------- graph segment boundaries from sorted batch ----------------
__global__ void k_bounds(const int* __restrict__ batch, int* __restrict__ gstart, int N) {
    int n = blockIdx.x * 256 + threadIdx.x;
    if (n > N) return;
    int bc = (n < N) ? batch[n] : NG;
    int bp = (n > 0) ? batch[n - 1] : -1;
    for (int g = bp + 1; g <= bc; ++g) gstart[g] = n;
}

// ---------------- fused weight prep: XW = embed@W1 -> fp16; wt2 = W2^T fp16 ---------
__global__ void k_prep(const float* __restrict__ embed, const float* __restrict__ W1,
                       const float* __restrict__ W2, __half* __restrict__ xw,
                       __half* __restrict__ wt2, int V, int xwBlocks) {
    if ((int)blockIdx.x < xwBlocks) {
        int v = (blockIdx.x * 256 + threadIdx.x) >> 6;
        if (v >= V) return;
        int lane = threadIdx.x & 63;
        float ev = embed[(size_t)v * EMB + lane];
        float a0 = 0.f, a1 = 0.f;
#pragma unroll
        for (int k = 0; k < EMB; ++k) {
            float e = __shfl(ev, k, 64);
            float2 w = *(const float2*)&W1[k * HID + 2 * lane];
            a0 = fmaf(e, w.x, a0);
            a1 = fmaf(e, w.y, a1);
        }
        ((__half2*)xw)[(size_t)v * 64 + lane] = __floats2half2_rn(a0, a1);
    } else {
        int i = (blockIdx.x - xwBlocks) * 256 + threadIdx.x;   // 64 blocks: 16384
        int c = i >> 7, k = i & 127;
        wt2[i] = __float2half(W2[k * HID + c]);
    }
}

// ---------------- layer-1: quarter-wave gather in XW space + bias + relu -> h1 ------
// h1[d] = relu( dd*( dd*XW[ids[d]] + sum_e dinv[s_e]*XW[vid_e] ) + b1 )
__global__ void k_gather1(const int* __restrict__ ids, const __half* __restrict__ xw,
                          const unsigned* __restrict__ csr32, const int* __restrict__ rowptr,
                          const float* __restrict__ dinv, const float* __restrict__ bias,
                          __half* __restrict__ h1, int N) {
    int d = (blockIdx.x * blockDim.x + threadIdx.x) >> 6;  // one wave per node
    if (d >= N) return;
    int lane = threadIdx.x & 63;
    int eg = lane >> 4, c = lane & 15;        // edge-group, 16B-chunk index
    int beg = rowptr[d], end = rowptr[d + 1];
    float dd = dinv[d];
    float a[8] = {0.f, 0.f, 0.f, 0.f, 0.f, 0.f, 0.f, 0.f};
    if (eg == 0) {                            // self term
        uint4 r = ((const uint4*)(xw + (size_t)ids[d] * HID))[c];
        fma8(a, r, dd);
    }
    int i = beg;
    for (; i + 16 <= end; i += 16) {          // 4 edges/group in flight
        unsigned p[4]; uint4 r[4]; float w[4];
#pragma unroll
        for (int j = 0; j < 4; ++j) p[j] = csr32[i + 4 * j + eg];
#pragma unroll
        for (int j = 0; j < 4; ++j) {
            w[j] = dinv[p[j] & ((1u << SRCBITS) - 1)];
            r[j] = ((const uint4*)(xw + (size_t)(p[j] >> SRCBITS) * HID))[c];
        }
#pragma unroll
        for (int j = 0; j < 4; ++j) fma8(a, r[j], w[j]);
    }
    for (; i + 4 <= end; i += 4) {
        unsigned p = csr32[i + eg];
        float w = dinv[p & ((1u << SRCBITS) - 1)];
        uint4 r = ((const uint4*)(xw + (size_t)(p >> SRCBITS) * HID))[c];
        fma8(a, r, w);
    }
    int rem = end - i;
    if (eg < rem) {
        unsigned p = csr32[i + eg];
        float w = dinv[p & ((1u << SRCBITS) - 1)];
        uint4 r = ((const uint4*)(xw + (size_t)(p >> SRCBITS) * HID))[c];
        fma8(a, r, w);
    }
#pragma unroll
    for (int k = 0; k < 8; ++k) {
        a[k] += __shfl_xor(a[k], 32, 64);
        a[k] += __shfl_xor(a[k], 16, 64);
    }
    if (eg == 0) {
        float4 bl = *(const float4*)&bias[c * 8];
        float4 bh = *(const float4*)&bias[c * 8 + 4];
        __half2 h0 = __floats2half2_rn(fmaxf(fmaf(a[0], dd, bl.x), 0.f),
                                       fmaxf(fmaf(a[1], dd, bl.y), 0.f));
        __half2 h1v = __floats2half2_rn(fmaxf(fmaf(a[2], dd, bl.z), 0.f),
                                        fmaxf(fmaf(a[3], dd, bl.w), 0.f));
        __half2 h2v = __floats2half2_rn(fmaxf(fmaf(a[4], dd, bh.x), 0.f),
                                        fmaxf(fmaf(a[5], dd, bh.y), 0.f));
        __half2 h3 = __floats2half2_rn(fmaxf(fmaf(a[6], dd, bh.z), 0.f),
                                       fmaxf(fmaf(a[7], dd, bh.w), 0.f));
        uint4 pk = make_uint4(*(unsigned*)&h0, *(unsigned*)&h1v,
                              *(unsigned*)&h2v, *(unsigned*)&h3);
        ((uint4*)(h1 + (size_t)d * HID))[c] = pk;
    }
}

// ---------------- layer-2 matmul via MFMA: h2 = (h1 @ W2) * dinv, fp16 ----------------
__global__ __launch_bounds__(256) void k_mm2_mfma(const __half* __restrict__ h1,
                                                  const __half* __restrict__ wt,
                                                  const float* __restrict__ dinv,
                                                  __half* __restrict__ h2, int N) {
    int tid = threadIdx.x;
    int w = tid >> 6, l = tid & 63;
    int base = blockIdx.x * MMB + w * 16;
    int lrow = l & 15, lkg = l >> 4;
    int arow = base + lrow; if (arow >= N) arow = N - 1;
    const f16x8* ap = (const f16x8*)(h1 + (size_t)arow * HID);
    f16x8 a0 = ap[0 * 4 + lkg], a1 = ap[1 * 4 + lkg];
    f16x8 a2 = ap[2 * 4 + lkg], a3 = ap[3 * 4 + lkg];
    f32x4 acc[8];
#pragma unroll
    for (int ct = 0; ct < 8; ++ct) acc[ct] = (f32x4){0.f, 0.f, 0.f, 0.f};
    const f16x8* wp = (const f16x8*)wt;   // wt[c][k]: row c = 16 f16x8 chunks
#pragma unroll
    for (int ct = 0; ct < 8; ++ct) {
        const f16x8* bp = wp + (ct * 16 + lrow) * 16 + lkg;
        f16x8 b0 = bp[0], b1 = bp[4], b2 = bp[8], b3 = bp[12];
        acc[ct] = __builtin_amdgcn_mfma_f32_16x16x32_f16(a0, b0, acc[ct], 0, 0, 0);
        acc[ct] = __builtin_amdgcn_mfma_f32_16x16x32_f16(a1, b1, acc[ct], 0, 0, 0);
        acc[ct] = __builtin_amdgcn_mfma_f32_16x16x32_f16(a2, b2, acc[ct], 0, 0, 0);
        acc[ct] = __builtin_amdgcn_mfma_f32_16x16x32_f16(a3, b3, acc[ct], 0, 0, 0);
    }
    int m0 = base + lkg * 4;
    float sc[4];
#pragma unroll
    for (int r = 0; r < 4; ++r) sc[r] = (m0 + r < N) ? dinv[m0 + r] : 0.f;
#pragma unroll
    for (int ct = 0; ct < 8; ++ct) {
        int c = ct * 16 + lrow;
#pragma unroll
        for (int r = 0; r < 4; ++r) {
            int m = m0 + r;
            if (m < N) h2[(size_t)m * HID + c] = __float2half(acc[ct][r] * sc[r]);
        }
    }
}

// ---------------- layer-2 quarter-wave gather: x2[d]=relu(dd*(h2[d]+sum h2[s])+b2) --
__global__ void k_gather2(const __half* __restrict__ h2, const unsigned* __restrict__ csr32,
                          const int* __restrict__ rowptr, const float* __restrict__ dinv,
                          const float* __restrict__ bias, __half* __restrict__ x2, int N) {
    int d = (blockIdx.x * blockDim.x + threadIdx.x) >> 6;  // one wave per node
    if (d >= N) return;
    int lane = threadIdx.x & 63;
    int eg = lane >> 4, c = lane & 15;
    int beg = rowptr[d], end = rowptr[d + 1];
    float dd = dinv[d];
    float a[8] = {0.f, 0.f, 0.f, 0.f, 0.f, 0.f, 0.f, 0.f};
    if (eg == 0) {                            // self term (prescaled by dinv already)
        uint4 r = ((const uint4*)(h2 + (size_t)d * HID))[c];
        acc8(a, r);
    }
    int i = beg;
    for (; i + 16 <= end; i += 16) {
        unsigned s[4]; uint4 r[4];
#pragma unroll
        for (int j = 0; j < 4; ++j) s[j] = csr32[i + 4 * j + eg] & ((1u << SRCBITS) - 1);
#pragma unroll
        for (int j = 0; j < 4; ++j) r[j] = ((const uint4*)(h2 + (size_t)s[j] * HID))[c];
#pragma unroll
        for (int j = 0; j < 4; ++j) acc8(a, r[j]);
    }
    for (; i + 4 <= end; i += 4) {
        unsigned s = csr32[i + eg] & ((1u << SRCBITS) - 1);
        uint4 r = ((const uint4*)(h2 + (size_t)s * HID))[c];
        acc8(a, r);
    }
    int rem = end - i;
    if (eg < rem) {
        unsigned s = csr32[i + eg] & ((1u << SRCBITS) - 1);
        uint4 r = ((const uint4*)(h2 + (size_t)s * HID))[c];
        acc8(a, r);
    }
#pragma unroll
    for (int k = 0; k < 8; ++k) {
        a[k] += __shfl_xor(a[k], 32, 64);
        a[k] += __shfl_xor(a[k], 16, 64);
    }
    if (eg == 0) {
        float4 bl = *(const float4*)&bias[c * 8];
        float4 bh = *(const float4*)&bias[c * 8 + 4];
        __half2 h0 = __floats2half2_rn(fmaxf(fmaf(a[0], dd, bl.x), 0.f),
                                       fmaxf(fmaf(a[1], dd, bl.y), 0.f));
        __half2 h1v = __floats2half2_rn(fmaxf(fmaf(a[2], dd, bl.z), 0.f),
                                        fmaxf(fmaf(a[3], dd, bl.w), 0.f));
        __half2 h2v = __floats2half2_rn(fmaxf(fmaf(a[4], dd, bh.x), 0.f),
                                        fmaxf(fmaf(a[5], dd, bh.y), 0.f));
        __half2 h3 = __floats2half2_rn(fmaxf(fmaf(a[6], dd, bh.z), 0.f),
                                       fmaxf(fmaf(a[7], dd, bh.w), 0.f));
        uint4 pk = make_uint4(*(unsigned*)&h0, *(unsigned*)&h1v,
                              *(unsigned*)&h2v, *(unsigned*)&h3);
        ((uint4*)(x2 + (size_t)d * HID))[c] = pk;
    }
}

// ---------------- mean-pool + head: one wave per graph, contiguous fp16 rows --------
__global__ void k_poolhead(const __half* __restrict__ x2, const int* __restrict__ gstart,
                           const float* __restrict__ Wout, const float* __restrict__ bout,
                           float* __restrict__ out) {
    int g = (blockIdx.x * blockDim.x + threadIdx.x) >> 6;  // graph id
    if (g >= NG) return;
    int lane = threadIdx.x & 63;
    int beg = gstart[g], end = gstart[g + 1];
    const __half2* rows = (const __half2*)x2;
    float sx = 0.f, sy = 0.f;
    for (int n = beg; n < end; ++n) {
        float2 v = __half22float2(rows[(size_t)n * 64 + lane]);
        sx += v.x; sy += v.y;
    }
    float inv = (end > beg) ? 1.f / (float)(end - beg) : 1.f;
    sx *= inv; sy *= inv;
    float wo0[NCLS], wo1[NCLS];
    {
        const float4* p0 = (const float4*)&Wout[(size_t)(2 * lane) * NCLS];
        const float4* p1 = (const float4*)&Wout[(size_t)(2 * lane + 1) * NCLS];
#pragma unroll
        for (int j = 0; j < 4; ++j) {
            float4 a = p0[j]; wo0[4*j] = a.x; wo0[4*j+1] = a.y; wo0[4*j+2] = a.z; wo0[4*j+3] = a.w;
            float4 c = p1[j]; wo1[4*j] = c.x; wo1[4*j+1] = c.y; wo1[4*j+2] = c.z; wo1[4*j+3] = c.w;
        }
    }
#pragma unroll
    for (int c = 0; c < NCLS; ++c) {
        float p = fmaf(sx, wo0[c], sy * wo1[c]);
#pragma unroll
        for (int s = 1; s < 64; s <<= 1) p += __shfl_xor(p, s, 64);
        if (lane == c) out[(size_t)g * NCLS + c] = p + bout[c];
    }
}

static inline size_t align_up(size_t v, size_t a) { return (v + a - 1) & ~(a - 1); }

extern "C" void kernel_launch(void* const* d_in, const int* in_sizes, int n_in,
                              void* d_out, int out_size, void* d_ws, size_t ws_size,
                              hipStream_t stream) {
    const int*   node_ids = (const int*)d_in[0];
    const int*   edge     = (const int*)d_in[1];
    const int*   batch    = (const int*)d_in[2];
    const float* embed    = (const float*)d_in[3];
    const float* W1       = (const float*)d_in[4];
    const float* b1       = (const float*)d_in[5];
    const float* W2       = (const float*)d_in[6];
    const float* b2       = (const float*)d_in[7];
    const float* Wout     = (const float*)d_in[8];
    const float* bout     = (const float*)d_in[9];
    float* out = (float*)d_out;

    const int N = in_sizes[0];
    const int E = in_sizes[1] / 2;
    const int V = in_sizes[3] / EMB;
    const int seg = (N + SCAN_T - 1) / SCAN_T;

    // 256B-aligned workspace layout (~83 MB)
    char* wsb = (char*)d_ws;
    size_t off = 0;
    float*    dinv   = (float*)(wsb + off);    off = align_up(off + (size_t)N * 4, 256);
    int*      deg    = (int*)(wsb + off);      off = align_up(off + (size_t)N * 4, 256);
    int*      rowptr = (int*)(wsb + off);      off = align_up(off + (size_t)(N + 1) * 4, 256);
    int*      tsum   = (int*)(wsb + off);      off = align_up(off + (size_t)SCAN_T * 4, 256);
    int*      gstart = (int*)(wsb + off);      off = align_up(off + (size_t)(NG + 1) * 4, 256);
    __half*   wt2    = (__half*)(wsb + off);   off = align_up(off + (size_t)HID * HID * 2, 256);
    __half*   xw     = (__half*)(wsb + off);   off = align_up(off + (size_t)V * HID * 2, 256);
    unsigned* csr32  = (unsigned*)(wsb + off); off = align_up(off + (size_t)E * 4, 256);
    __half*   h1     = (__half*)(wsb + off);   off = align_up(off + (size_t)N * HID * 2, 256);
    __half*   h2     = (__half*)(wsb + off);   off = align_up(off + (size_t)N * HID * 2, 256);
    __half*   x2     = (__half*)(wsb + off);   off = align_up(off + (size_t)N * HID * 2, 256);

    const int* src = edge;
    const int* dst = edge + E;

    // ---- CSR build + boundaries + weight prep ----
    hipMemsetAsync(deg, 0, (size_t)N * 4, stream);
    k_deg<<<(E + 255) / 256, 256, 0, stream>>>(dst, E, deg);
    k_scanA<<<SCAN_T / 256, 256, 0, stream>>>(deg, tsum, N, seg);
    k_scanB<<<1, 256, 0, stream>>>(tsum);
    k_scanC<<<SCAN_T / 256, 256, 0, stream>>>(deg, tsum, rowptr, dinv, N, seg, E);
    hipMemsetAsync(deg, 0, (size_t)N * 4, stream);   // reuse as cursor
    k_fill<<<(E + 255) / 256, 256, 0, stream>>>(src, dst, node_ids, rowptr, deg, csr32, E);
    k_bounds<<<(N + 1 + 255) / 256, 256, 0, stream>>>(batch, gstart, N);
    {
        int xwBlocks = (V * 64 + 255) / 256;
        k_prep<<<xwBlocks + 64, 256, 0, stream>>>(embed, W1, W2, xw, wt2, V, xwBlocks);
    }

    // ---- layer 1: quarter-wave gather in XW space (bias+relu fused) -> h1 fp16 ----
    k_gather1<<<(N * 64 + 255) / 256, 256, 0, stream>>>(node_ids, xw, csr32, rowptr,
                                                        dinv, b1, h1, N);

    // ---- layer 2: MFMA matmul -> fp16 (prescaled by dinv), then quarter-wave gather ----
    k_mm2_mfma<<<(N + MMB - 1) / MMB, 256, 0, stream>>>(h1, wt2, dinv, h2, N);
    k_gather2<<<(N * 64 + 255) / 256, 256, 0, stream>>>(h2, csr32, rowptr, dinv, b2, x2, N);

    // ---- mean-pool + head ----
    k_poolhead<<<(NG * 64 + 255) / 256, 256, 0, stream>>>(x2, gstart, Wout, bout, out);
}

// Round 13
// 249.636 us; speedup vs baseline: 1.3077x; 1.1202x over previous
//
#include <hip/hip_runtime.h>
#include <hip/hip_fp16.h>

#define HID 128
#define EMB 64
#define NG  8192
#define NCLS 16
#define SCAN_T 4096
#define MMB 64        // nodes per matmul block
#define SRCBITS 17    // N=100000 < 2^17; VOCAB=5000 < 2^13

typedef _Float16 f16x8 __attribute__((ext_vector_type(8)));
typedef float    f32x4 __attribute__((ext_vector_type(4)));

__device__ __forceinline__ void acc8(float* a, uint4 r) {
    float2 f0 = __half22float2(*(const __half2*)&r.x);
    float2 f1 = __half22float2(*(const __half2*)&r.y);
    float2 f2 = __half22float2(*(const __half2*)&r.z);
    float2 f3 = __half22float2(*(const __half2*)&r.w);
    a[0] += f0.x; a[1] += f0.y; a[2] += f1.x; a[3] += f1.y;
    a[4] += f2.x; a[5] += f2.y; a[6] += f3.x; a[7] += f3.y;
}

__device__ __forceinline__ void fma8(float* a, uint4 r, float w) {
    float2 f0 = __half22float2(*(const __half2*)&r.x);
    float2 f1 = __half22float2(*(const __half2*)&r.y);
    float2 f2 = __half22float2(*(const __half2*)&r.z);
    float2 f3 = __half22float2(*(const __half2*)&r.w);
    a[0] = fmaf(f0.x, w, a[0]); a[1] = fmaf(f0.y, w, a[1]);
    a[2] = fmaf(f1.x, w, a[2]); a[3] = fmaf(f1.y, w, a[3]);
    a[4] = fmaf(f2.x, w, a[4]); a[5] = fmaf(f2.y, w, a[5]);
    a[6] = fmaf(f3.x, w, a[6]); a[7] = fmaf(f3.y, w, a[7]);
}

// ---------------- degree + slot index (atomic returns the slot) ----------------
__global__ void k_deg(const int* __restrict__ dst, int E, int* __restrict__ deg,
                      int* __restrict__ epos) {
    int i = blockIdx.x * 256 + threadIdx.x;
    if (i < E) epos[i] = atomicAdd(&deg[dst[i]], 1);
}

// ---------------- exclusive scan of deg -> rowptr (+ dinv fused in C) ----------------
__global__ void k_scanA(const int* __restrict__ deg, int* __restrict__ tsum, int N, int seg) {
    int t = blockIdx.x * 256 + threadIdx.x;
    int beg = t * seg, end = min(beg + seg, N);
    int s = 0;
    for (int i = beg; i < end; ++i) s += deg[i];
    tsum[t] = s;
}

__global__ void k_scanB(int* __restrict__ tsum) {
    __shared__ int sh[256];
    int tid = threadIdx.x;
    const int PER = SCAN_T / 256;
    int vals[PER];
    int local = 0;
    int base = tid * PER;
#pragma unroll
    for (int i = 0; i < PER; ++i) { vals[i] = tsum[base + i]; local += vals[i]; }
    sh[tid] = local; __syncthreads();
    for (int d = 1; d < 256; d <<= 1) {
        int v = (tid >= d) ? sh[tid - d] : 0;
        __syncthreads();
        sh[tid] += v;
        __syncthreads();
    }
    int off = sh[tid] - local;
#pragma unroll
    for (int i = 0; i < PER; ++i) { int v = vals[i]; tsum[base + i] = off; off += v; }
}

__global__ void k_scanC(const int* __restrict__ deg, const int* __restrict__ tsum,
                        int* __restrict__ rowptr, float* __restrict__ dinv,
                        int N, int seg, int E) {
    int t = blockIdx.x * 256 + threadIdx.x;
    int beg = t * seg, end = min(beg + seg, N);
    int off = tsum[t];
    for (int i = beg; i < end; ++i) {
        int dg = deg[i];
        rowptr[i] = off; off += dg;
        dinv[i] = rsqrtf((float)(dg + 1));   // +1 self-loop
    }
    if (t == 0) rowptr[N] = E;
}

// ---------------- CSR fill: atomic-free scatter, 4 edges/thread ----------------
__global__ void k_fill(const int* __restrict__ src, const int* __restrict__ dst,
                       const int* __restrict__ ids, const int* __restrict__ rowptr,
                       const int* __restrict__ epos, unsigned* __restrict__ csr32, int E) {
    int e4 = (blockIdx.x * 256 + threadIdx.x) * 4;
    if (e4 + 4 <= E) {
        int4 s4 = *(const int4*)&src[e4];
        int4 d4 = *(const int4*)&dst[e4];
        int4 p4 = *(const int4*)&epos[e4];
        csr32[rowptr[d4.x] + p4.x] = ((unsigned)ids[s4.x] << SRCBITS) | (unsigned)s4.x;
        csr32[rowptr[d4.y] + p4.y] = ((unsigned)ids[s4.y] << SRCBITS) | (unsigned)s4.y;
        csr32[rowptr[d4.z] + p4.z] = ((unsigned)ids[s4.z] << SRCBITS) | (unsigned)s4.z;
        csr32[rowptr[d4.w] + p4.w] = ((unsigned)ids[s4.w] << SRCBITS) | (unsigned)s4.w;
    } else {
        for (int e = e4; e < E; ++e) {
            int s = src[e], d = dst[e];
            csr32[rowptr[d] + epos[e]] = ((unsigned)ids[s] << SRCBITS) | (unsigned)s;
        }
    }
}

// ---------------- graph segment boundaries from sorted batch ----------------
__global__ void k_bounds(const int* __restrict__ batch, int* __restrict__ gstart, int N) {
    int n = blockIdx.x * 256 + threadIdx.x;
    if (n > N) return;
    int bc = (n < N) ? batch[n] : NG;
    int bp = (n > 0) ? batch[n - 1] : -1;
    for (int g = bp + 1; g <= bc; ++g) gstart[g] = n;
}

// ---------------- fused weight prep: XW = embed@W1 -> fp16; wt2 = W2^T fp16 ---------
__global__ void k_prep(const float* __restrict__ embed, const float* __restrict__ W1,
                       const float* __restrict__ W2, __half* __restrict__ xw,
                       __half* __restrict__ wt2, int V, int xwBlocks) {
    if ((int)blockIdx.x < xwBlocks) {
        int v = (blockIdx.x * 256 + threadIdx.x) >> 6;
        if (v >= V) return;
        int lane = threadIdx.x & 63;
        float ev = embed[(size_t)v * EMB + lane];
        float a0 = 0.f, a1 = 0.f;
#pragma unroll
        for (int k = 0; k < EMB; ++k) {
            float e = __shfl(ev, k, 64);
            float2 w = *(const float2*)&W1[k * HID + 2 * lane];
            a0 = fmaf(e, w.x, a0);
            a1 = fmaf(e, w.y, a1);
        }
        ((__half2*)xw)[(size_t)v * 64 + lane] = __floats2half2_rn(a0, a1);
    } else {
        int i = (blockIdx.x - xwBlocks) * 256 + threadIdx.x;   // 64 blocks: 16384
        int c = i >> 7, k = i & 127;
        wt2[i] = __float2half(W2[k * HID + c]);
    }
}

// ---------------- layer-1: quarter-wave gather in XW space + bias + relu -> h1 ------
__global__ void k_gather1(const int* __restrict__ ids, const __half* __restrict__ xw,
                          const unsigned* __restrict__ csr32, const int* __restrict__ rowptr,
                          const float* __restrict__ dinv, const float* __restrict__ bias,
                          __half* __restrict__ h1, int N) {
    int d = (blockIdx.x * blockDim.x + threadIdx.x) >> 6;  // one wave per node
    if (d >= N) return;
    int lane = threadIdx.x & 63;
    int eg = lane >> 4, c = lane & 15;        // edge-group, 16B-chunk index
    int beg = rowptr[d], end = rowptr[d + 1];
    float dd = dinv[d];
    float a[8] = {0.f, 0.f, 0.f, 0.f, 0.f, 0.f, 0.f, 0.f};
    if (eg == 0) {                            // self term
        uint4 r = ((const uint4*)(xw + (size_t)ids[d] * HID))[c];
        fma8(a, r, dd);
    }
    int i = beg;
    for (; i + 16 <= end; i += 16) {          // 4 edges/group in flight
        unsigned p[4]; uint4 r[4]; float w[4];
#pragma unroll
        for (int j = 0; j < 4; ++j) p[j] = csr32[i + 4 * j + eg];
#pragma unroll
        for (int j = 0; j < 4; ++j) {
            w[j] = dinv[p[j] & ((1u << SRCBITS) - 1)];
            r[j] = ((const uint4*)(xw + (size_t)(p[j] >> SRCBITS) * HID))[c];
        }
#pragma unroll
        for (int j = 0; j < 4; ++j) fma8(a, r[j], w[j]);
    }
    for (; i + 4 <= end; i += 4) {
        unsigned p = csr32[i + eg];
        float w = dinv[p & ((1u << SRCBITS) - 1)];
        uint4 r = ((const uint4*)(xw + (size_t)(p >> SRCBITS) * HID))[c];
        fma8(a, r, w);
    }
    int rem = end - i;
    if (eg < rem) {
        unsigned p = csr32[i + eg];
        float w = dinv[p & ((1u << SRCBITS) - 1)];
        uint4 r = ((const uint4*)(xw + (size_t)(p >> SRCBITS) * HID))[c];
        fma8(a, r, w);
    }
#pragma unroll
    for (int k = 0; k < 8; ++k) {
        a[k] += __shfl_xor(a[k], 32, 64);
        a[k] += __shfl_xor(a[k], 16, 64);
    }
    if (eg == 0) {
        float4 bl = *(const float4*)&bias[c * 8];
        float4 bh = *(const float4*)&bias[c * 8 + 4];
        __half2 h0 = __floats2half2_rn(fmaxf(fmaf(a[0], dd, bl.x), 0.f),
                                       fmaxf(fmaf(a[1], dd, bl.y), 0.f));
        __half2 h1v = __floats2half2_rn(fmaxf(fmaf(a[2], dd, bl.z), 0.f),
                                        fmaxf(fmaf(a[3], dd, bl.w), 0.f));
        __half2 h2v = __floats2half2_rn(fmaxf(fmaf(a[4], dd, bh.x), 0.f),
                                        fmaxf(fmaf(a[5], dd, bh.y), 0.f));
        __half2 h3 = __floats2half2_rn(fmaxf(fmaf(a[6], dd, bh.z), 0.f),
                                       fmaxf(fmaf(a[7], dd, bh.w), 0.f));
        uint4 pk = make_uint4(*(unsigned*)&h0, *(unsigned*)&h1v,
                              *(unsigned*)&h2v, *(unsigned*)&h3);
        ((uint4*)(h1 + (size_t)d * HID))[c] = pk;
    }
}

// ---------------- layer-2 matmul via MFMA: h2 = (h1 @ W2) * dinv, fp16 ----------------
__global__ __launch_bounds__(256) void k_mm2_mfma(const __half* __restrict__ h1,
                                                  const __half* __restrict__ wt,
                                                  const float* __restrict__ dinv,
                                                  __half* __restrict__ h2, int N) {
    int tid = threadIdx.x;
    int w = tid >> 6, l = tid & 63;
    int base = blockIdx.x * MMB + w * 16;
    int lrow = l & 15, lkg = l >> 4;
    int arow = base + lrow; if (arow >= N) arow = N - 1;
    const f16x8* ap = (const f16x8*)(h1 + (size_t)arow * HID);
    f16x8 a0 = ap[0 * 4 + lkg], a1 = ap[1 * 4 + lkg];
    f16x8 a2 = ap[2 * 4 + lkg], a3 = ap[3 * 4 + lkg];
    f32x4 acc[8];
#pragma unroll
    for (int ct = 0; ct < 8; ++ct) acc[ct] = (f32x4){0.f, 0.f, 0.f, 0.f};
    const f16x8* wp = (const f16x8*)wt;   // wt[c][k]: row c = 16 f16x8 chunks
#pragma unroll
    for (int ct = 0; ct < 8; ++ct) {
        const f16x8* bp = wp + (ct * 16 + lrow) * 16 + lkg;
        f16x8 b0 = bp[0], b1 = bp[4], b2 = bp[8], b3 = bp[12];
        acc[ct] = __builtin_amdgcn_mfma_f32_16x16x32_f16(a0, b0, acc[ct], 0, 0, 0);
        acc[ct] = __builtin_amdgcn_mfma_f32_16x16x32_f16(a1, b1, acc[ct], 0, 0, 0);
        acc[ct] = __builtin_amdgcn_mfma_f32_16x16x32_f16(a2, b2, acc[ct], 0, 0, 0);
        acc[ct] = __builtin_amdgcn_mfma_f32_16x16x32_f16(a3, b3, acc[ct], 0, 0, 0);
    }
    int m0 = base + lkg * 4;
    float sc[4];
#pragma unroll
    for (int r = 0; r < 4; ++r) sc[r] = (m0 + r < N) ? dinv[m0 + r] : 0.f;
#pragma unroll
    for (int ct = 0; ct < 8; ++ct) {
        int c = ct * 16 + lrow;
#pragma unroll
        for (int r = 0; r < 4; ++r) {
            int m = m0 + r;
            if (m < N) h2[(size_t)m * HID + c] = __float2half(acc[ct][r] * sc[r]);
        }
    }
}

// ---------------- layer-2 quarter-wave gather: x2[d]=relu(dd*(h2[d]+sum h2[s])+b2) --
__global__ void k_gather2(const __half* __restrict__ h2, const unsigned* __restrict__ csr32,
                          const int* __restrict__ rowptr, const float* __restrict__ dinv,
                          const float* __restrict__ bias, __half* __restrict__ x2, int N) {
    int d = (blockIdx.x * blockDim.x + threadIdx.x) >> 6;  // one wave per node
    if (d >= N) return;
    int lane = threadIdx.x & 63;
    int eg = lane >> 4, c = lane & 15;
    int beg = rowptr[d], end = rowptr[d + 1];
    float dd = dinv[d];
    float a[8] = {0.f, 0.f, 0.f, 0.f, 0.f, 0.f, 0.f, 0.f};
    if (eg == 0) {                            // self term (prescaled by dinv already)
        uint4 r = ((const uint4*)(h2 + (size_t)d * HID))[c];
        acc8(a, r);
    }
    int i = beg;
    for (; i + 16 <= end; i += 16) {
        unsigned s[4]; uint4 r[4];
#pragma unroll
        for (int j = 0; j < 4; ++j) s[j] = csr32[i + 4 * j + eg] & ((1u << SRCBITS) - 1);
#pragma unroll
        for (int j = 0; j < 4; ++j) r[j] = ((const uint4*)(h2 + (size_t)s[j] * HID))[c];
#pragma unroll
        for (int j = 0; j < 4; ++j) acc8(a, r[j]);
    }
    for (; i + 4 <= end; i += 4) {
        unsigned s = csr32[i + eg] & ((1u << SRCBITS) - 1);
        uint4 r = ((const uint4*)(h2 + (size_t)s * HID))[c];
        acc8(a, r);
    }
    int rem = end - i;
    if (eg < rem) {
        unsigned s = csr32[i + eg] & ((1u << SRCBITS) - 1);
        uint4 r = ((const uint4*)(h2 + (size_t)s * HID))[c];
        acc8(a, r);
    }
#pragma unroll
    for (int k = 0; k < 8; ++k) {
        a[k] += __shfl_xor(a[k], 32, 64);
        a[k] += __shfl_xor(a[k], 16, 64);
    }
    if (eg == 0) {
        float4 bl = *(const float4*)&bias[c * 8];
        float4 bh = *(const float4*)&bias[c * 8 + 4];
        __half2 h0 = __floats2half2_rn(fmaxf(fmaf(a[0], dd, bl.x), 0.f),
                                       fmaxf(fmaf(a[1], dd, bl.y), 0.f));
        __half2 h1v = __floats2half2_rn(fmaxf(fmaf(a[2], dd, bl.z), 0.f),
                                        fmaxf(fmaf(a[3], dd, bl.w), 0.f));
        __half2 h2v = __floats2half2_rn(fmaxf(fmaf(a[4], dd, bh.x), 0.f),
                                        fmaxf(fmaf(a[5], dd, bh.y), 0.f));
        __half2 h3 = __floats2half2_rn(fmaxf(fmaf(a[6], dd, bh.z), 0.f),
                                       fmaxf(fmaf(a[7], dd, bh.w), 0.f));
        uint4 pk = make_uint4(*(unsigned*)&h0, *(unsigned*)&h1v,
                              *(unsigned*)&h2v, *(unsigned*)&h3);
        ((uint4*)(x2 + (size_t)d * HID))[c] = pk;
    }
}

// ---------------- mean-pool + head: one wave per graph, contiguous fp16 rows --------
__global__ void k_poolhead(const __half* __restrict__ x2, const int* __restrict__ gstart,
                           const float* __restrict__ Wout, const float* __restrict__ bout,
                           float* __restrict__ out) {
    int g = (blockIdx.x * blockDim.x + threadIdx.x) >> 6;  // graph id
    if (g >= NG) return;
    int lane = threadIdx.x & 63;
    int beg = gstart[g], end = gstart[g + 1];
    const __half2* rows = (const __half2*)x2;
    float sx = 0.f, sy = 0.f;
    for (int n = beg; n < end; ++n) {
        float2 v = __half22float2(rows[(size_t)n * 64 + lane]);
        sx += v.x; sy += v.y;
    }
    float inv = (end > beg) ? 1.f / (float)(end - beg) : 1.f;
    sx *= inv; sy *= inv;
    float wo0[NCLS], wo1[NCLS];
    {
        const float4* p0 = (const float4*)&Wout[(size_t)(2 * lane) * NCLS];
        const float4* p1 = (const float4*)&Wout[(size_t)(2 * lane + 1) * NCLS];
#pragma unroll
        for (int j = 0; j < 4; ++j) {
            float4 a = p0[j]; wo0[4*j] = a.x; wo0[4*j+1] = a.y; wo0[4*j+2] = a.z; wo0[4*j+3] = a.w;
            float4 c = p1[j]; wo1[4*j] = c.x; wo1[4*j+1] = c.y; wo1[4*j+2] = c.z; wo1[4*j+3] = c.w;
        }
    }
#pragma unroll
    for (int c = 0; c < NCLS; ++c) {
        float p = fmaf(sx, wo0[c], sy * wo1[c]);
#pragma unroll
        for (int s = 1; s < 64; s <<= 1) p += __shfl_xor(p, s, 64);
        if (lane == c) out[(size_t)g * NCLS + c] = p + bout[c];
    }
}

static inline size_t align_up(size_t v, size_t a) { return (v + a - 1) & ~(a - 1); }

extern "C" void kernel_launch(void* const* d_in, const int* in_sizes, int n_in,
                              void* d_out, int out_size, void* d_ws, size_t ws_size,
                              hipStream_t stream) {
    const int*   node_ids = (const int*)d_in[0];
    const int*   edge     = (const int*)d_in[1];
    const int*   batch    = (const int*)d_in[2];
    const float* embed    = (const float*)d_in[3];
    const float* W1       = (const float*)d_in[4];
    const float* b1       = (const float*)d_in[5];
    const float* W2       = (const float*)d_in[6];
    const float* b2       = (const float*)d_in[7];
    const float* Wout     = (const float*)d_in[8];
    const float* bout     = (const float*)d_in[9];
    float* out = (float*)d_out;

    const int N = in_sizes[0];
    const int E = in_sizes[1] / 2;
    const int V = in_sizes[3] / EMB;
    const int seg = (N + SCAN_T - 1) / SCAN_T;

    // 256B-aligned workspace layout (~87 MB)
    char* wsb = (char*)d_ws;
    size_t off = 0;
    float*    dinv   = (float*)(wsb + off);    off = align_up(off + (size_t)N * 4, 256);
    int*      deg    = (int*)(wsb + off);      off = align_up(off + (size_t)N * 4, 256);
    int*      rowptr = (int*)(wsb + off);      off = align_up(off + (size_t)(N + 1) * 4, 256);
    int*      tsum   = (int*)(wsb + off);      off = align_up(off + (size_t)SCAN_T * 4, 256);
    int*      gstart = (int*)(wsb + off);      off = align_up(off + (size_t)(NG + 1) * 4, 256);
    __half*   wt2    = (__half*)(wsb + off);   off = align_up(off + (size_t)HID * HID * 2, 256);
    __half*   xw     = (__half*)(wsb + off);   off = align_up(off + (size_t)V * HID * 2, 256);
    int*      epos   = (int*)(wsb + off);      off = align_up(off + (size_t)E * 4, 256);
    unsigned* csr32  = (unsigned*)(wsb + off); off = align_up(off + (size_t)E * 4, 256);
    __half*   h1     = (__half*)(wsb + off);   off = align_up(off + (size_t)N * HID * 2, 256);
    __half*   h2     = (__half*)(wsb + off);   off = align_up(off + (size_t)N * HID * 2, 256);
    __half*   x2     = (__half*)(wsb + off);   off = align_up(off + (size_t)N * HID * 2, 256);

    const int* src = edge;
    const int* dst = edge + E;

    // ---- CSR build + boundaries + weight prep ----
    hipMemsetAsync(deg, 0, (size_t)N * 4, stream);
    k_deg<<<(E + 255) / 256, 256, 0, stream>>>(dst, E, deg, epos);
    k_scanA<<<SCAN_T / 256, 256, 0, stream>>>(deg, tsum, N, seg);
    k_scanB<<<1, 256, 0, stream>>>(tsum);
    k_scanC<<<SCAN_T / 256, 256, 0, stream>>>(deg, tsum, rowptr, dinv, N, seg, E);
    k_fill<<<(E / 4 + 255) / 256, 256, 0, stream>>>(src, dst, node_ids, rowptr, epos, csr32, E);
    k_bounds<<<(N + 1 + 255) / 256, 256, 0, stream>>>(batch, gstart, N);
    {
        int xwBlocks = (V * 64 + 255) / 256;
        k_prep<<<xwBlocks + 64, 256, 0, stream>>>(embed, W1, W2, xw, wt2, V, xwBlocks);
    }

    // ---- layer 1: quarter-wave gather in XW space (bias+relu fused) -> h1 fp16 ----
    k_gather1<<<(N * 64 + 255) / 256, 256, 0, stream>>>(node_ids, xw, csr32, rowptr,
                                                        dinv, b1, h1, N);

    // ---- layer 2: MFMA matmul -> fp16 (prescaled by dinv), then quarter-wave gather ----
    k_mm2_mfma<<<(N + MMB - 1) / MMB, 256, 0, stream>>>(h1, wt2, dinv, h2, N);
    k_gather2<<<(N * 64 + 255) / 256, 256, 0, stream>>>(h2, csr32, rowptr, dinv, b2, x2, N);

    // ---- mean-pool + head ----
    k_poolhead<<<(NG * 64 + 255) / 256, 256, 0, stream>>>(x2, gstart, Wout, bout, out);
}

// Round 14
// 240.492 us; speedup vs baseline: 1.3575x; 1.0380x over previous
//
#include <hip/hip_runtime.h>
#include <hip/hip_fp16.h>

#define HID 128
#define EMB 64
#define NG  8192
#define NCLS 16
#define SCAN_T 4096
#define MMB 64        // nodes per matmul block
#define SRCBITS 17    // N=100000 < 2^17; VOCAB=5000 < 2^13
#define SMASK ((1u << SRCBITS) - 1)

typedef _Float16 f16x8 __attribute__((ext_vector_type(8)));
typedef float    f32x4 __attribute__((ext_vector_type(4)));

__device__ __forceinline__ void fma8(float* a, uint4 r, float w) {
    float2 f0 = __half22float2(*(const __half2*)&r.x);
    float2 f1 = __half22float2(*(const __half2*)&r.y);
    float2 f2 = __half22float2(*(const __half2*)&r.z);
    float2 f3 = __half22float2(*(const __half2*)&r.w);
    a[0] = fmaf(f0.x, w, a[0]); a[1] = fmaf(f0.y, w, a[1]);
    a[2] = fmaf(f1.x, w, a[2]); a[3] = fmaf(f1.y, w, a[3]);
    a[4] = fmaf(f2.x, w, a[4]); a[5] = fmaf(f2.y, w, a[5]);
    a[6] = fmaf(f3.x, w, a[6]); a[7] = fmaf(f3.y, w, a[7]);
}

// ---------------- degree + slot index (atomic returns the slot) ----------------
__global__ void k_deg(const int* __restrict__ dst, int E, int* __restrict__ deg,
                      int* __restrict__ epos) {
    int i = blockIdx.x * 256 + threadIdx.x;
    if (i < E) epos[i] = atomicAdd(&deg[dst[i]], 1);
}

// ---------------- exclusive scan of deg -> rowptr (+ dinv fused in C) ----------------
__global__ void k_scanA(const int* __restrict__ deg, int* __restrict__ tsum, int N, int seg) {
    int t = blockIdx.x * 256 + threadIdx.x;
    int beg = t * seg, end = min(beg + seg, N);
    int s = 0;
    for (int i = beg; i < end; ++i) s += deg[i];
    tsum[t] = s;
}

__global__ void k_scanB(int* __restrict__ tsum) {
    __shared__ int sh[256];
    int tid = threadIdx.x;
    const int PER = SCAN_T / 256;
    int vals[PER];
    int local = 0;
    int base = tid * PER;
#pragma unroll
    for (int i = 0; i < PER; ++i) { vals[i] = tsum[base + i]; local += vals[i]; }
    sh[tid] = local; __syncthreads();
    for (int d = 1; d < 256; d <<= 1) {
        int v = (tid >= d) ? sh[tid - d] : 0;
        __syncthreads();
        sh[tid] += v;
        __syncthreads();
    }
    int off = sh[tid] - local;
#pragma unroll
    for (int i = 0; i < PER; ++i) { int v = vals[i]; tsum[base + i] = off; off += v; }
}

__global__ void k_scanC(const int* __restrict__ deg, const int* __restrict__ tsum,
                        int* __restrict__ rowptr, float* __restrict__ dinv,
                        int N, int seg, int E) {
    int t = blockIdx.x * 256 + threadIdx.x;
    int beg = t * seg, end = min(beg + seg, N);
    int off = tsum[t];
    for (int i = beg; i < end; ++i) {
        int dg = deg[i];
        rowptr[i] = off; off += dg;
        dinv[i] = rsqrtf((float)(dg + 1));   // +1 self-loop
    }
    if (t == 0) rowptr[N] = E;
}

// ---------------- CSR fill: atomic-free scatter, 4 edges/thread ----------------
__global__ void k_fill(const int* __restrict__ src, const int* __restrict__ dst,
                       const int* __restrict__ ids, const int* __restrict__ rowptr,
                       const int* __restrict__ epos, unsigned* __restrict__ csr32, int E) {
    int e4 = (blockIdx.x * 256 + threadIdx.x) * 4;
    if (e4 + 4 <= E) {
        int4 s4 = *(const int4*)&src[e4];
        int4 d4 = *(const int4*)&dst[e4];
        int4 p4 = *(const int4*)&epos[e4];
        csr32[rowptr[d4.x] + p4.x] = ((unsigned)ids[s4.x] << SRCBITS) | (unsigned)s4.x;
        csr32[rowptr[d4.y] + p4.y] = ((unsigned)ids[s4.y] << SRCBITS) | (unsigned)s4.y;
        csr32[rowptr[d4.z] + p4.z] = ((unsigned)ids[s4.z] << SRCBITS) | (unsigned)s4.z;
        csr32[rowptr[d4.w] + p4.w] = ((unsigned)ids[s4.w] << SRCBITS) | (unsigned)s4.w;
    } else {
        for (int e = e4; e < E; ++e) {
            int s = src[e], d = dst[e];
            csr32[rowptr[d] + epos[e]] = ((unsigned)ids[s] << SRCBITS) | (unsigned)s;
        }
    }
}

// ---------------- fused prep: XW = embed@W1 fp16; wt2 = W2^T fp16; graph bounds -----
__global__ void k_prep(const float* __restrict__ embed, const float* __restrict__ W1,
                       const float* __restrict__ W2, const int* __restrict__ batch,
                       __half* __restrict__ xw, __half* __restrict__ wt2,
                       int* __restrict__ gstart, int V, int N, int xwBlocks) {
    int b = (int)blockIdx.x;
    if (b < xwBlocks) {
        int v = (b * 256 + threadIdx.x) >> 6;
        if (v >= V) return;
        int lane = threadIdx.x & 63;
        float ev = embed[(size_t)v * EMB + lane];
        float a0 = 0.f, a1 = 0.f;
#pragma unroll
        for (int k = 0; k < EMB; ++k) {
            float e = __shfl(ev, k, 64);
            float2 w = *(const float2*)&W1[k * HID + 2 * lane];
            a0 = fmaf(e, w.x, a0);
            a1 = fmaf(e, w.y, a1);
        }
        ((__half2*)xw)[(size_t)v * 64 + lane] = __floats2half2_rn(a0, a1);
    } else if (b < xwBlocks + 64) {
        int i = (b - xwBlocks) * 256 + threadIdx.x;   // 64 blocks: 16384
        int c = i >> 7, k = i & 127;
        wt2[i] = __float2half(W2[k * HID + c]);
    } else {
        int n = (b - xwBlocks - 64) * 256 + threadIdx.x;
        if (n > N) return;
        int bc = (n < N) ? batch[n] : NG;
        int bp = (n > 0) ? batch[n - 1] : -1;
        for (int g = bp + 1; g <= bc; ++g) gstart[g] = n;
    }
}

// ---------------- layer-1: predicated quarter-wave gather + bias + relu -> h1 -------
// h1[d] = relu( dd*( dd*XW[ids[d]] + sum_e dinv[s_e]*XW[vid_e] ) + b1 )
// Every iteration issues 4 row-loads; invalid edges masked to row 0 / w=0.
__global__ void k_gather1(const int* __restrict__ ids, const __half* __restrict__ xw,
                          const unsigned* __restrict__ csr32, const int* __restrict__ rowptr,
                          const float* __restrict__ dinv, const float* __restrict__ bias,
                          __half* __restrict__ h1, int N) {
    int d = (blockIdx.x * blockDim.x + threadIdx.x) >> 6;  // one wave per node
    if (d >= N) return;
    int lane = threadIdx.x & 63;
    int eg = lane >> 4, c = lane & 15;        // edge-group, 16B-chunk index
    int beg = rowptr[d], end = rowptr[d + 1];
    float dd = dinv[d];
    float a[8] = {0.f, 0.f, 0.f, 0.f, 0.f, 0.f, 0.f, 0.f};
    if (eg == 0) {                            // self term
        uint4 r = ((const uint4*)(xw + (size_t)ids[d] * HID))[c];
        fma8(a, r, dd);
    }
    for (int i = beg; i < end; i += 16) {     // ALWAYS 4 row-loads in flight
        float w[4]; unsigned vr[4]; uint4 r[4];
#pragma unroll
        for (int j = 0; j < 4; ++j) {
            int idx = i + 4 * j + eg;
            bool v = idx < end;
            unsigned p = csr32[v ? idx : beg];
            w[j] = v ? dinv[p & SMASK] : 0.f;
            vr[j] = v ? (p >> SRCBITS) : 0u;
        }
#pragma unroll
        for (int j = 0; j < 4; ++j) r[j] = ((const uint4*)(xw + (size_t)vr[j] * HID))[c];
#pragma unroll
        for (int j = 0; j < 4; ++j) fma8(a, r[j], w[j]);
    }
#pragma unroll
    for (int k = 0; k < 8; ++k) {
        a[k] += __shfl_xor(a[k], 32, 64);
        a[k] += __shfl_xor(a[k], 16, 64);
    }
    if (eg == 0) {
        float4 bl = *(const float4*)&bias[c * 8];
        float4 bh = *(const float4*)&bias[c * 8 + 4];
        __half2 h0 = __floats2half2_rn(fmaxf(fmaf(a[0], dd, bl.x), 0.f),
                                       fmaxf(fmaf(a[1], dd, bl.y), 0.f));
        __half2 h1v = __floats2half2_rn(fmaxf(fmaf(a[2], dd, bl.z), 0.f),
                                        fmaxf(fmaf(a[3], dd, bl.w), 0.f));
        __half2 h2v = __floats2half2_rn(fmaxf(fmaf(a[4], dd, bh.x), 0.f),
                                        fmaxf(fmaf(a[5], dd, bh.y), 0.f));
        __half2 h3 = __floats2half2_rn(fmaxf(fmaf(a[6], dd, bh.z), 0.f),
                                       fmaxf(fmaf(a[7], dd, bh.w), 0.f));
        uint4 pk = make_uint4(*(unsigned*)&h0, *(unsigned*)&h1v,
                              *(unsigned*)&h2v, *(unsigned*)&h3);
        ((uint4*)(h1 + (size_t)d * HID))[c] = pk;
    }
}

// ---------------- layer-2 matmul via MFMA: h2 = (h1 @ W2) * dinv, fp16 ----------------
__global__ __launch_bounds__(256) void k_mm2_mfma(const __half* __restrict__ h1,
                                                  const __half* __restrict__ wt,
                                                  const float* __restrict__ dinv,
                                                  __half* __restrict__ h2, int N) {
    int tid = threadIdx.x;
    int w = tid >> 6, l = tid & 63;
    int base = blockIdx.x * MMB + w * 16;
    int lrow = l & 15, lkg = l >> 4;
    int arow = base + lrow; if (arow >= N) arow = N - 1;
    const f16x8* ap = (const f16x8*)(h1 + (size_t)arow * HID);
    f16x8 a0 = ap[0 * 4 + lkg], a1 = ap[1 * 4 + lkg];
    f16x8 a2 = ap[2 * 4 + lkg], a3 = ap[3 * 4 + lkg];
    f32x4 acc[8];
#pragma unroll
    for (int ct = 0; ct < 8; ++ct) acc[ct] = (f32x4){0.f, 0.f, 0.f, 0.f};
    const f16x8* wp = (const f16x8*)wt;   // wt[c][k]: row c = 16 f16x8 chunks
#pragma unroll
    for (int ct = 0; ct < 8; ++ct) {
        const f16x8* bp = wp + (ct * 16 + lrow) * 16 + lkg;
        f16x8 b0 = bp[0], b1 = bp[4], b2 = bp[8], b3 = bp[12];
        acc[ct] = __builtin_amdgcn_mfma_f32_16x16x32_f16(a0, b0, acc[ct], 0, 0, 0);
        acc[ct] = __builtin_amdgcn_mfma_f32_16x16x32_f16(a1, b1, acc[ct], 0, 0, 0);
        acc[ct] = __builtin_amdgcn_mfma_f32_16x16x32_f16(a2, b2, acc[ct], 0, 0, 0);
        acc[ct] = __builtin_amdgcn_mfma_f32_16x16x32_f16(a3, b3, acc[ct], 0, 0, 0);
    }
    int m0 = base + lkg * 4;
    float sc[4];
#pragma unroll
    for (int r = 0; r < 4; ++r) sc[r] = (m0 + r < N) ? dinv[m0 + r] : 0.f;
#pragma unroll
    for (int ct = 0; ct < 8; ++ct) {
        int c = ct * 16 + lrow;
#pragma unroll
        for (int r = 0; r < 4; ++r) {
            int m = m0 + r;
            if (m < N) h2[(size_t)m * HID + c] = __float2half(acc[ct][r] * sc[r]);
        }
    }
}

// ---------------- layer-2 predicated gather: x2[d]=relu(dd*(h2[d]+sum h2[s])+b2) ----
__global__ void k_gather2(const __half* __restrict__ h2, const unsigned* __restrict__ csr32,
                          const int* __restrict__ rowptr, const float* __restrict__ dinv,
                          const float* __restrict__ bias, __half* __restrict__ x2, int N) {
    int d = (blockIdx.x * blockDim.x + threadIdx.x) >> 6;  // one wave per node
    if (d >= N) return;
    int lane = threadIdx.x & 63;
    int eg = lane >> 4, c = lane & 15;
    int beg = rowptr[d], end = rowptr[d + 1];
    float dd = dinv[d];
    float a[8] = {0.f, 0.f, 0.f, 0.f, 0.f, 0.f, 0.f, 0.f};
    if (eg == 0) {                            // self term (prescaled by dinv already)
        uint4 r = ((const uint4*)(h2 + (size_t)d * HID))[c];
        fma8(a, r, 1.f);
    }
    for (int i = beg; i < end; i += 16) {     // ALWAYS 4 row-loads in flight
        float w[4]; unsigned sr[4]; uint4 r[4];
#pragma unroll
        for (int j = 0; j < 4; ++j) {
            int idx = i + 4 * j + eg;
            bool v = idx < end;
            unsigned p = csr32[v ? idx : beg];
            w[j] = v ? 1.f : 0.f;
            sr[j] = v ? (p & SMASK) : 0u;
        }
#pragma unroll
        for (int j = 0; j < 4; ++j) r[j] = ((const uint4*)(h2 + (size_t)sr[j] * HID))[c];
#pragma unroll
        for (int j = 0; j < 4; ++j) fma8(a, r[j], w[j]);
    }
#pragma unroll
    for (int k = 0; k < 8; ++k) {
        a[k] += __shfl_xor(a[k], 32, 64);
        a[k] += __shfl_xor(a[k], 16, 64);
    }
    if (eg == 0) {
        float4 bl = *(const float4*)&bias[c * 8];
        float4 bh = *(const float4*)&bias[c * 8 + 4];
        __half2 h0 = __floats2half2_rn(fmaxf(fmaf(a[0], dd, bl.x), 0.f),
                                       fmaxf(fmaf(a[1], dd, bl.y), 0.f));
        __half2 h1v = __floats2half2_rn(fmaxf(fmaf(a[2], dd, bl.z), 0.f),
                                        fmaxf(fmaf(a[3], dd, bl.w), 0.f));
        __half2 h2v = __floats2half2_rn(fmaxf(fmaf(a[4], dd, bh.x), 0.f),
                                        fmaxf(fmaf(a[5], dd, bh.y), 0.f));
        __half2 h3 = __floats2half2_rn(fmaxf(fmaf(a[6], dd, bh.z), 0.f),
                                       fmaxf(fmaf(a[7], dd, bh.w), 0.f));
        uint4 pk = make_uint4(*(unsigned*)&h0, *(unsigned*)&h1v,
                              *(unsigned*)&h2v, *(unsigned*)&h3);
        ((uint4*)(x2 + (size_t)d * HID))[c] = pk;
    }
}

// ---------------- mean-pool + head: one wave per graph, contiguous fp16 rows --------
__global__ void k_poolhead(const __half* __restrict__ x2, const int* __restrict__ gstart,
                           const float* __restrict__ Wout, const float* __restrict__ bout,
                           float* __restrict__ out) {
    int g = (blockIdx.x * blockDim.x + threadIdx.x) >> 6;  // graph id
    if (g >= NG) return;
    int lane = threadIdx.x & 63;
    int beg = gstart[g], end = gstart[g + 1];
    const __half2* rows = (const __half2*)x2;
    float sx = 0.f, sy = 0.f;
    for (int n = beg; n < end; ++n) {
        float2 v = __half22float2(rows[(size_t)n * 64 + lane]);
        sx += v.x; sy += v.y;
    }
    float inv = (end > beg) ? 1.f / (float)(end - beg) : 1.f;
    sx *= inv; sy *= inv;
    float wo0[NCLS], wo1[NCLS];
    {
        const float4* p0 = (const float4*)&Wout[(size_t)(2 * lane) * NCLS];
        const float4* p1 = (const float4*)&Wout[(size_t)(2 * lane + 1) * NCLS];
#pragma unroll
        for (int j = 0; j < 4; ++j) {
            float4 a = p0[j]; wo0[4*j] = a.x; wo0[4*j+1] = a.y; wo0[4*j+2] = a.z; wo0[4*j+3] = a.w;
            float4 c = p1[j]; wo1[4*j] = c.x; wo1[4*j+1] = c.y; wo1[4*j+2] = c.z; wo1[4*j+3] = c.w;
        }
    }
#pragma unroll
    for (int c = 0; c < NCLS; ++c) {
        float p = fmaf(sx, wo0[c], sy * wo1[c]);
#pragma unroll
        for (int s = 1; s < 64; s <<= 1) p += __shfl_xor(p, s, 64);
        if (lane == c) out[(size_t)g * NCLS + c] = p + bout[c];
    }
}

static inline size_t align_up(size_t v, size_t a) { return (v + a - 1) & ~(a - 1); }

extern "C" void kernel_launch(void* const* d_in, const int* in_sizes, int n_in,
                              void* d_out, int out_size, void* d_ws, size_t ws_size,
                              hipStream_t stream) {
    const int*   node_ids = (const int*)d_in[0];
    const int*   edge     = (const int*)d_in[1];
    const int*   batch    = (const int*)d_in[2];
    const float* embed    = (const float*)d_in[3];
    const float* W1       = (const float*)d_in[4];
    const float* b1       = (const float*)d_in[5];
    const float* W2       = (const float*)d_in[6];
    const float* b2       = (const float*)d_in[7];
    const float* Wout     = (const float*)d_in[8];
    const float* bout     = (const float*)d_in[9];
    float* out = (float*)d_out;

    const int N = in_sizes[0];
    const int E = in_sizes[1] / 2;
    const int V = in_sizes[3] / EMB;
    const int seg = (N + SCAN_T - 1) / SCAN_T;

    // 256B-aligned workspace layout (~87 MB)
    char* wsb = (char*)d_ws;
    size_t off = 0;
    float*    dinv   = (float*)(wsb + off);    off = align_up(off + (size_t)N * 4, 256);
    int*      deg    = (int*)(wsb + off);      off = align_up(off + (size_t)N * 4, 256);
    int*      rowptr = (int*)(wsb + off);      off = align_up(off + (size_t)(N + 1) * 4, 256);
    int*      tsum   = (int*)(wsb + off);      off = align_up(off + (size_t)SCAN_T * 4, 256);
    int*      gstart = (int*)(wsb + off);      off = align_up(off + (size_t)(NG + 1) * 4, 256);
    __half*   wt2    = (__half*)(wsb + off);   off = align_up(off + (size_t)HID * HID * 2, 256);
    __half*   xw     = (__half*)(wsb + off);   off = align_up(off + (size_t)V * HID * 2, 256);
    int*      epos   = (int*)(wsb + off);      off = align_up(off + (size_t)E * 4, 256);
    unsigned* csr32  = (unsigned*)(wsb + off); off = align_up(off + (size_t)E * 4, 256);
    __half*   h1     = (__half*)(wsb + off);   off = align_up(off + (size_t)N * HID * 2, 256);
    __half*   h2     = (__half*)(wsb + off);   off = align_up(off + (size_t)N * HID * 2, 256);
    __half*   x2     = (__half*)(wsb + off);   off = align_up(off + (size_t)N * HID * 2, 256);

    const int* src = edge;
    const int* dst = edge + E;

    // ---- CSR build + prep ----
    hipMemsetAsync(deg, 0, (size_t)N * 4, stream);
    k_deg<<<(E + 255) / 256, 256, 0, stream>>>(dst, E, deg, epos);
    k_scanA<<<SCAN_T / 256, 256, 0, stream>>>(deg, tsum, N, seg);
    k_scanB<<<1, 256, 0, stream>>>(tsum);
    k_scanC<<<SCAN_T / 256, 256, 0, stream>>>(deg, tsum, rowptr, dinv, N, seg, E);
    k_fill<<<(E / 4 + 255) / 256, 256, 0, stream>>>(src, dst, node_ids, rowptr, epos, csr32, E);
    {
        int xwBlocks = (V * 64 + 255) / 256;
        int bndBlocks = (N + 1 + 255) / 256;
        k_prep<<<xwBlocks + 64 + bndBlocks, 256, 0, stream>>>(embed, W1, W2, batch,
                                                              xw, wt2, gstart, V, N, xwBlocks);
    }

    // ---- layer 1: predicated gather in XW space (bias+relu fused) -> h1 fp16 ----
    k_gather1<<<(N * 64 + 255) / 256, 256, 0, stream>>>(node_ids, xw, csr32, rowptr,
                                                        dinv, b1, h1, N);

    // ---- layer 2: MFMA matmul -> fp16 (prescaled by dinv), then predicated gather ----
    k_mm2_mfma<<<(N + MMB - 1) / MMB, 256, 0, stream>>>(h1, wt2, dinv, h2, N);
    k_gather2<<<(N * 64 + 255) / 256, 256, 0, stream>>>(h2, csr32, rowptr, dinv, b2, x2, N);

    // ---- mean-pool + head ----
    k_poolhead<<<(NG * 64 + 255) / 256, 256, 0, stream>>>(x2, gstart, Wout, bout, out);
}